// Round 2
// baseline (1192.533 us; speedup 1.0000x reference)
//
#include <hip/hip_runtime.h>

#define HW 65536
#define CH 40

// ---- conv 3x3, pad 1, C=40 -> C=40, fp32 --------------------------------
// ACT: 0 none, 1 gelu(exact), 2 relu ; RES: add fp32 residual AFTER act
template<int ACT, bool RES>
__global__ __launch_bounds__(256)
void conv3x3_k(const float* __restrict__ in, const float* __restrict__ w,
               const float* __restrict__ bias, const float* __restrict__ res,
               float* __restrict__ out)
{
  __shared__ float s_in[20 * 342];   // 20 ic x 18 rows x (18+1 pad) fp32
  __shared__ float s_w[20 * 400];    // [ic][oc][10 padded] fp32, per-chunk

  const int tid = threadIdx.x;
  const int bid = blockIdx.x;
  const int n = bid >> 8;            // 256 tiles per image
  const int tile = bid & 255;
  const int ty = (tile >> 4) << 4;
  const int tx = (tile & 15) << 4;

  const float* inp = in + (size_t)n * CH * HW;

  const int g = tid >> 6;        // oc-group: 4 groups x 10 oc
  const int l = tid & 63;
  const int py = l >> 2;         // 0..15
  const int px = (l & 3) << 2;   // 0,4,8,12
  const int ocb = g * 10;

  float acc[10][4];
  #pragma unroll
  for (int o = 0; o < 10; ++o)
    #pragma unroll
    for (int j = 0; j < 4; ++j) acc[o][j] = 0.f;

  for (int c0 = 0; c0 < 40; c0 += 20) {
    __syncthreads();               // protect s_in/s_w reuse across chunks
    // stage 20 ic x 18x18 input tile
    for (int i = tid; i < 20 * 324; i += 256) {
      int ic = i / 324;
      int r = i - ic * 324;
      int yy = r / 18;
      int xx = r - yy * 18;
      int gy = ty + yy - 1, gx = tx + xx - 1;
      float v = 0.f;
      if ((unsigned)gy < 256u && (unsigned)gx < 256u)
        v = inp[(c0 + ic) * HW + (gy << 8) + gx];
      s_in[ic * 342 + yy * 19 + xx] = v;
    }
    // stage weights for this ic chunk: [ic][oc][9] -> stride 10
    for (int i = tid; i < 7200; i += 256) {
      int ic = i / 360;
      int r = i - ic * 360;
      int oc = r / 9;
      int t = r - oc * 9;
      s_w[(ic * 40 + oc) * 10 + t] = w[oc * 360 + (c0 + ic) * 9 + t];
    }
    __syncthreads();

    for (int ic = 0; ic < 20; ++ic) {
      float iv[3][6];
      #pragma unroll
      for (int dy = 0; dy < 3; ++dy) {
        const float* ip = &s_in[ic * 342 + (py + dy) * 19 + px];
        #pragma unroll
        for (int xx = 0; xx < 6; ++xx) iv[dy][xx] = ip[xx];
      }
      #pragma unroll
      for (int o = 0; o < 10; ++o) {
        const float* wp = &s_w[(ic * 40 + ocb + o) * 10];
        float w00 = wp[0], w01 = wp[1], w02 = wp[2];
        float w10 = wp[3], w11 = wp[4], w12 = wp[5];
        float w20 = wp[6], w21 = wp[7], w22 = wp[8];
        #pragma unroll
        for (int j = 0; j < 4; ++j) {
          acc[o][j] += w00 * iv[0][j] + w01 * iv[0][j + 1] + w02 * iv[0][j + 2]
                     + w10 * iv[1][j] + w11 * iv[1][j + 1] + w12 * iv[1][j + 2]
                     + w20 * iv[2][j] + w21 * iv[2][j + 1] + w22 * iv[2][j + 2];
        }
      }
    }
  }

  const int oy = ty + py, ox = tx + px;
  #pragma unroll
  for (int o = 0; o < 10; ++o) {
    const int oc = ocb + o;
    const int oidx = ((n * CH + oc) << 16) + (oy << 8) + ox;
    const float bv = bias[oc];
    float4 rv = make_float4(0.f, 0.f, 0.f, 0.f);
    if (RES) rv = *(const float4*)&res[oidx];
    float v[4];
    #pragma unroll
    for (int j = 0; j < 4; ++j) {
      float t = acc[o][j] + bv;
      if (ACT == 1) t = 0.5f * t * (1.f + erff(t * 0.70710678118654752f));
      else if (ACT == 2) t = fmaxf(t, 0.f);
      if (RES) t += (&rv.x)[j];
      v[j] = t;
    }
    *(float4*)&out[oidx] = make_float4(v[0], v[1], v[2], v[3]);
  }
}

// ---- depthwise conv k3, stride 8, pad 2, dilation 2: 256x256 -> 32x32 ---
__global__ __launch_bounds__(256)
void dwconv_k(const float* __restrict__ in, const float* __restrict__ w,
              const float* __restrict__ b, float* __restrict__ out)
{
  int idx = blockIdx.x * 256 + threadIdx.x;   // 8*40*32*32 = 327680
  if (idx >= 8 * CH * 32 * 32) return;
  int ox = idx & 31;
  int oy = (idx >> 5) & 31;
  int bc = idx >> 10;          // n*40 + c
  int c = bc % CH;
  float acc = b[c];
  const float* ip = in + (size_t)bc * HW;
  #pragma unroll
  for (int dy = 0; dy < 3; ++dy) {
    int y = oy * 8 - 2 + dy * 2;
    if ((unsigned)y >= 256u) continue;
    #pragma unroll
    for (int dx = 0; dx < 3; ++dx) {
      int x = ox * 8 - 2 + dx * 2;
      if ((unsigned)x >= 256u) continue;
      acc += w[c * 9 + dy * 3 + dx] * ip[(y << 8) + x];
    }
  }
  out[idx] = acc;
}

// ---- per-8x8-block iDCT (Re(ifft ortho) both axes) on 32x32 -------------
__global__ __launch_bounds__(256)
void idct8_k(const float* __restrict__ in, float* __restrict__ out)
{
  __shared__ float ctab[8];
  if (threadIdx.x < 8) {
    const float c_[8] = {1.f, 0.70710678118654752f, 0.f, -0.70710678118654752f,
                         -1.f, -0.70710678118654752f, 0.f, 0.70710678118654752f};
    ctab[threadIdx.x] = c_[threadIdx.x];
  }
  __syncthreads();
  int idx = blockIdx.x * 256 + threadIdx.x;
  if (idx >= 8 * CH * 32 * 32) return;
  int ox = idx & 31, oy = (idx >> 5) & 31, bc = idx >> 10;
  int k = oy & 7, lq = ox & 7;
  const float* ip = in + bc * 1024 + (oy & ~7) * 32 + (ox & ~7);
  float acc = 0.f;
  #pragma unroll
  for (int m = 0; m < 8; ++m) {
    float rk = ctab[(k * m) & 7];
    float s = 0.f;
    #pragma unroll
    for (int nn = 0; nn < 8; ++nn)
      s += ctab[(lq * nn) & 7] * ip[m * 32 + nn];
    acc += rk * s;
  }
  out[idx] = acc * 0.125f;   // (1/sqrt(8))^2
}

// ---- 1x1 conv + sigmoid, fused bilinear upsample (32->256) + multiply ---
__global__ __launch_bounds__(256)
void wgtmul_k(const float* __restrict__ t1, const float* __restrict__ w3,
              const float* __restrict__ b3, const float* __restrict__ dct,
              float* __restrict__ out)
{
  __shared__ float s_w[1600];
  __shared__ float s_b[40];
  int tid = threadIdx.x;
  for (int i = tid; i < 1600; i += 256) s_w[i] = w3[i];
  if (tid < 40) s_b[tid] = b3[tid];
  __syncthreads();
  int g = tid >> 6, l = tid & 63;
  int ocb = g * 10;
  int pix = blockIdx.x * 256 + l * 4;   // flat (n,y,x), 4 consecutive x
  int n = pix >> 16;
  int y = (pix >> 8) & 255;
  int x = pix & 255;
  const float* tp = t1 + (size_t)n * CH * HW + (y << 8) + x;

  float acc[10][4];
  #pragma unroll
  for (int o = 0; o < 10; ++o) {
    float bv = s_b[ocb + o];
    #pragma unroll
    for (int j = 0; j < 4; ++j) acc[o][j] = bv;
  }
  for (int ic = 0; ic < 40; ++ic) {
    float4 v = *(const float4*)(tp + ic * HW);
    #pragma unroll
    for (int o = 0; o < 10; ++o) {
      float wv = s_w[(ocb + o) * 40 + ic];
      acc[o][0] += wv * v.x; acc[o][1] += wv * v.y;
      acc[o][2] += wv * v.z; acc[o][3] += wv * v.w;
    }
  }

  float sy = (y + 0.5f) * 0.125f - 0.5f;
  int y0 = (int)floorf(sy);
  float fy = sy - (float)y0;
  int y0c = max(y0, 0), y1c = min(y0 + 1, 31);
  int x0c[4], x1c[4]; float fx[4];
  #pragma unroll
  for (int j = 0; j < 4; ++j) {
    float sx = (x + j + 0.5f) * 0.125f - 0.5f;
    int x0 = (int)floorf(sx);
    fx[j] = sx - (float)x0;
    x0c[j] = max(x0, 0); x1c[j] = min(x0 + 1, 31);
  }
  #pragma unroll
  for (int o = 0; o < 10; ++o) {
    int oc = ocb + o;
    const float* sp = dct + (n * CH + oc) * 1024;
    const float* r0 = sp + y0c * 32;
    const float* r1 = sp + y1c * 32;
    float rs[4];
    #pragma unroll
    for (int j = 0; j < 4; ++j) {
      float wgt = 1.f / (1.f + expf(-acc[o][j]));
      float v00 = r0[x0c[j]], v01 = r0[x1c[j]];
      float v10 = r1[x0c[j]], v11 = r1[x1c[j]];
      float bil = (1.f - fy) * ((1.f - fx[j]) * v00 + fx[j] * v01)
                +         fy * ((1.f - fx[j]) * v10 + fx[j] * v11);
      rs[j] = wgt * bil;
    }
    *(float4*)(out + ((n * CH + oc) << 16) + (y << 8) + x) =
        make_float4(rs[0], rs[1], rs[2], rs[3]);
  }
}

extern "C" void kernel_launch(void* const* d_in, const int* in_sizes, int n_in,
                              void* d_out, int out_size, void* d_ws, size_t ws_size,
                              hipStream_t stream)
{
  const float* x       = (const float*)d_in[0];
  const float* conv_w  = (const float*)d_in[1];
  const float* conv_b  = (const float*)d_in[2];
  const float* ddct_w  = (const float*)d_in[3];
  const float* ddct_b  = (const float*)d_in[4];
  const float* dctc_w  = (const float*)d_in[5];
  const float* dctc_b  = (const float*)d_in[6];
  const float* w1_w    = (const float*)d_in[7];
  const float* w1_b    = (const float*)d_in[8];
  const float* w3_w    = (const float*)d_in[9];
  const float* w3_b    = (const float*)d_in[10];
  const float* after_w = (const float*)d_in[11];
  const float* after_b = (const float*)d_in[12];

  float* outf = (float*)d_out;          // also used as scratch (dd, t1)
  char* ws = (char*)d_ws;
  float* buf0   = (float*)ws;                       // 83,886,080 B
  float* small0 = (float*)(ws + 83886080);          // 1,310,720 B
  float* small1 = (float*)(ws + 85196800);          // 1,310,720 B

  // 1. dct_feat = gelu(conv(x))                  -> buf0
  conv3x3_k<1, false><<<2048, 256, 0, stream>>>(x, conv_w, conv_b, nullptr, buf0);
  // 2. dd = gelu(conv(dct_feat)) + dct_feat      -> d_out (scratch)
  conv3x3_k<1, true><<<2048, 256, 0, stream>>>(buf0, ddct_w, ddct_b, buf0, outf);
  // 3. depthwise strided conv                    -> small0 (8,40,32,32)
  dwconv_k<<<1280, 256, 0, stream>>>(outf, dctc_w, dctc_b, small0);
  // 4. per-block 8x8 iDCT                        -> small1
  idct8_k<<<1280, 256, 0, stream>>>(small0, small1);
  // 5. t1 = relu(conv(x, w1))                    -> d_out (dd dead)
  conv3x3_k<2, false><<<2048, 256, 0, stream>>>(x, w1_w, w1_b, nullptr, outf);
  // 6. prod = sigmoid(1x1(t1)) * bilinear(idct)  -> buf0 (dct_feat dead)
  wgtmul_k<<<2048, 256, 0, stream>>>(outf, w3_w, w3_b, small1, buf0);
  // 7. out = conv(prod, after)                   -> d_out
  conv3x3_k<0, false><<<2048, 256, 0, stream>>>(buf0, after_w, after_b, nullptr, outf);
}

// Round 3
// 377.183 us; speedup vs baseline: 3.1617x; 3.1617x over previous
//
#include <hip/hip_runtime.h>

typedef unsigned short u16;
typedef unsigned int u32;
typedef __attribute__((ext_vector_type(8))) short bf16x8;
typedef __attribute__((ext_vector_type(4))) float f32x4;

#define CH 40
#define IW 258                   // ring-padded width (256 + 2)
#define IMG_CL (IW * IW * CH)    // u16 elements per image, channel-last padded
#define WT_SET (48 * 384)        // u16 per weight set

__device__ __forceinline__ float b2f(u16 u) {
  union { u32 i; float f; } v; v.i = ((u32)u) << 16; return v.f;
}
__device__ __forceinline__ float lo16(u32 u) {
  union { u32 i; float f; } v; v.i = u << 16; return v.f;
}
__device__ __forceinline__ float hi16(u32 u) {
  union { u32 i; float f; } v; v.i = u & 0xffff0000u; return v.f;
}
__device__ __forceinline__ u16 f2b(float f) {
  union { float f; u32 i; } v; v.f = f;
  u32 r = v.i + 0x7fffu + ((v.i >> 16) & 1u);
  return (u16)(r >> 16);
}

// ---- weights fp32 [oc40][ic40][3][3] -> Wt bf16 [48][384], k = dy*128+dx*40+ic
__global__ __launch_bounds__(256)
void prep_w_k(const float* __restrict__ w0, const float* __restrict__ w1,
              const float* __restrict__ w2, const float* __restrict__ w3,
              u16* __restrict__ wt)
{
  int i = blockIdx.x * 256 + threadIdx.x;      // 4*48*384 = 73728
  if (i >= 4 * WT_SET) return;
  int k = i % 384;
  int oc = (i / 384) % 48;
  int set = i / WT_SET;
  int dy = k >> 7;
  int r = k & 127;
  u16 v = 0;
  if (oc < 40 && r < 120) {
    int dx = r / 40;
    int ic = r - dx * 40;
    const float* w = (set == 0) ? w0 : (set == 1) ? w1 : (set == 2) ? w2 : w3;
    v = f2b(w[((oc * 40 + ic) * 3 + dy) * 3 + dx]);
  }
  wt[i] = v;
}

// ---- x fp32 planar -> xcl bf16 channel-last + zero rings of all 3 cl bufs
__global__ __launch_bounds__(256)
void prep_x_k(const float* __restrict__ x, u16* __restrict__ xcl,
              u16* __restrict__ cla, u16* __restrict__ clb)
{
  const int n = blockIdx.x / IW;
  const int yr = blockIdx.x % IW;          // padded row 0..257
  const int t = threadIdx.x;
  const size_t base = (size_t)n * IMG_CL + (size_t)yr * (IW * CH);
  const uint4 z = {0u, 0u, 0u, 0u};

  if (yr == 0 || yr == IW - 1) {           // full ring row: IW*CH u16 = 1290 x 16B
    for (int i = t; i < (IW * CH) / 8; i += 256) {
      ((uint4*)(xcl + base))[i] = z;
      ((uint4*)(cla + base))[i] = z;
      ((uint4*)(clb + base))[i] = z;
    }
    return;
  }
  if (t < 5) {                             // left ring col (40 u16 = 5 x 16B)
    ((uint4*)(xcl + base))[t] = z;
    ((uint4*)(cla + base))[t] = z;
    ((uint4*)(clb + base))[t] = z;
  } else if (t < 10) {                     // right ring col
    size_t b2 = base + (size_t)(IW - 1) * CH;
    ((uint4*)(xcl + b2))[t - 5] = z;
    ((uint4*)(cla + b2))[t - 5] = z;
    ((uint4*)(clb + b2))[t - 5] = z;
  }
  // interior: y = yr-1, thread t handles x = t
  const int y = yr - 1;
  const float* xp = x + (size_t)n * CH * 65536 + (size_t)y * 256 + t;
  __attribute__((aligned(16))) u16 buf[40];
  #pragma unroll
  for (int ic = 0; ic < 40; ++ic) buf[ic] = f2b(xp[(size_t)ic * 65536]);
  u16* dst = xcl + base + (size_t)(t + 1) * CH;
  #pragma unroll
  for (int q = 0; q < 5; ++q) ((uint4*)dst)[q] = ((const uint4*)buf)[q];
}

// ---- MFMA implicit-GEMM conv 3x3 pad 1, cl bf16 in, cl bf16 / planar f32 out
// ACT: 0 none, 1 gelu(exact), 2 relu ; RES: add bf16 cl residual after act
template<int ACT, bool RES, bool PLANAR_OUT>
__global__ __launch_bounds__(256)
void convm_k(const u16* __restrict__ incl, const u16* __restrict__ wt,
             const float* __restrict__ bias, const u16* __restrict__ rescl,
             void* __restrict__ outp)
{
  __shared__ u16 s_in[6 * 66 * CH];        // 15840 u16 = 31680 B

  const int tid = threadIdx.x;
  const int bid = blockIdx.x;
  const int n = bid >> 8;
  const int tb = bid & 255;
  const int y0 = (tb >> 2) << 2;           // 64 y-tiles of 4 rows
  const int x0 = (tb & 3) << 6;            // 4 x-tiles of 64 px

  // stage (y0-1..y0+4) x (x0-1..x0+64) x 40ic from ring-padded cl buffer
  const u16* src = incl + (size_t)n * IMG_CL + ((size_t)y0 * IW + x0) * CH;
  for (int i = tid; i < 1980; i += 256) {  // 6 rows x 330 chunks of 16B
    int r = i / 330;
    int o = i - r * 330;
    uint4 v = *(const uint4*)(src + (size_t)r * (IW * CH) + o * 8);
    *(uint4*)(s_in + r * (66 * CH) + o * 8) = v;
  }
  __syncthreads();

  const int w = tid >> 6;                  // wave -> output row y0+w
  const int l = tid & 63;
  const int g = l >> 4;                    // lane group 0..3
  const int m = l & 15;

  f32x4 acc[4][3];
  #pragma unroll
  for (int xt = 0; xt < 4; ++xt)
    #pragma unroll
    for (int t = 0; t < 3; ++t) acc[xt][t] = (f32x4){0.f, 0.f, 0.f, 0.f};

  #pragma unroll
  for (int s = 0; s < 12; ++s) {
    const int dy = s >> 2;
    const int c = ((s & 3) << 2) + g;      // k-chunk id 0..15
    int dx, icb;
    if (c >= 15)      { dx = 0; icb = 0; }     // zero-weight pad chunk
    else if (c >= 10) { dx = 2; icb = (c - 10) * 8; }
    else if (c >= 5)  { dx = 1; icb = (c - 5) * 8; }
    else              { dx = 0; icb = c * 8; }

    const int abase = (w + dy) * (66 * CH) + (m + dx) * CH + icb;
    bf16x8 a0 = *(const bf16x8*)(s_in + abase);
    bf16x8 a1 = *(const bf16x8*)(s_in + abase + 16 * CH);
    bf16x8 a2 = *(const bf16x8*)(s_in + abase + 32 * CH);
    bf16x8 a3 = *(const bf16x8*)(s_in + abase + 48 * CH);

    const int wb = s * 32 + g * 8;
    bf16x8 b0 = *(const bf16x8*)(wt + (m     ) * 384 + wb);
    bf16x8 b1 = *(const bf16x8*)(wt + (m + 16) * 384 + wb);
    bf16x8 b2 = *(const bf16x8*)(wt + (m + 32) * 384 + wb);

    acc[0][0] = __builtin_amdgcn_mfma_f32_16x16x32_bf16(a0, b0, acc[0][0], 0, 0, 0);
    acc[1][0] = __builtin_amdgcn_mfma_f32_16x16x32_bf16(a1, b0, acc[1][0], 0, 0, 0);
    acc[2][0] = __builtin_amdgcn_mfma_f32_16x16x32_bf16(a2, b0, acc[2][0], 0, 0, 0);
    acc[3][0] = __builtin_amdgcn_mfma_f32_16x16x32_bf16(a3, b0, acc[3][0], 0, 0, 0);
    acc[0][1] = __builtin_amdgcn_mfma_f32_16x16x32_bf16(a0, b1, acc[0][1], 0, 0, 0);
    acc[1][1] = __builtin_amdgcn_mfma_f32_16x16x32_bf16(a1, b1, acc[1][1], 0, 0, 0);
    acc[2][1] = __builtin_amdgcn_mfma_f32_16x16x32_bf16(a2, b1, acc[2][1], 0, 0, 0);
    acc[3][1] = __builtin_amdgcn_mfma_f32_16x16x32_bf16(a3, b1, acc[3][1], 0, 0, 0);
    acc[0][2] = __builtin_amdgcn_mfma_f32_16x16x32_bf16(a0, b2, acc[0][2], 0, 0, 0);
    acc[1][2] = __builtin_amdgcn_mfma_f32_16x16x32_bf16(a1, b2, acc[1][2], 0, 0, 0);
    acc[2][2] = __builtin_amdgcn_mfma_f32_16x16x32_bf16(a2, b2, acc[2][2], 0, 0, 0);
    acc[3][2] = __builtin_amdgcn_mfma_f32_16x16x32_bf16(a3, b2, acc[3][2], 0, 0, 0);
  }

  const int y = y0 + w;
  const float bv0 = bias[m];
  const float bv1 = bias[m + 16];
  const float bv2 = (m < 8) ? bias[m + 32] : 0.f;

  #pragma unroll
  for (int t = 0; t < 3; ++t) {
    const int oc = m + 16 * t;
    if (t == 2 && m >= 8) continue;        // oc >= 40: padding
    const float bv = (t == 0) ? bv0 : (t == 1) ? bv1 : bv2;
    #pragma unroll
    for (int xt = 0; xt < 4; ++xt) {
      const int xb = x0 + xt * 16 + 4 * g; // rows 4g..4g+3 of D = consecutive x
      float v[4];
      #pragma unroll
      for (int i = 0; i < 4; ++i) {
        float tv = acc[xt][t][i] + bv;
        if (ACT == 1) tv = 0.5f * tv * (1.f + erff(tv * 0.70710678118654752f));
        else if (ACT == 2) tv = fmaxf(tv, 0.f);
        v[i] = tv;
      }
      if (RES) {
        const u16* rp = rescl + (size_t)n * IMG_CL + ((size_t)(y + 1) * IW + (xb + 1)) * CH + oc;
        #pragma unroll
        for (int i = 0; i < 4; ++i) v[i] += b2f(rp[(size_t)i * CH]);
      }
      if (PLANAR_OUT) {
        float4 st = make_float4(v[0], v[1], v[2], v[3]);
        *(float4*)((float*)outp + (((size_t)(n * CH + oc)) << 16) + ((size_t)y << 8) + xb) = st;
      } else {
        u16* op = (u16*)outp + (size_t)n * IMG_CL + ((size_t)(y + 1) * IW + (xb + 1)) * CH + oc;
        #pragma unroll
        for (int i = 0; i < 4; ++i) op[(size_t)i * CH] = f2b(v[i]);
      }
    }
  }
}

// ---- depthwise conv k3 s8 p2 d2 on cl bf16 -> planar f32 (8,40,32,32) ----
__global__ __launch_bounds__(256)
void dwconv_k(const u16* __restrict__ incl, const float* __restrict__ w,
              const float* __restrict__ b, float* __restrict__ out)
{
  int idx = blockIdx.x * 256 + threadIdx.x;   // (((n*32+oy)*32)+ox)*40 + c
  if (idx >= 8 * 32 * 32 * CH) return;
  int c = idx % CH;
  int p = idx / CH;
  int ox = p & 31;
  int oy = (p >> 5) & 31;
  int n = p >> 10;
  float acc = b[c];
  const u16* ip = incl + (size_t)n * IMG_CL;
  #pragma unroll
  for (int dy = 0; dy < 3; ++dy) {
    int y = oy * 8 - 2 + dy * 2;
    if ((unsigned)y >= 256u) continue;
    #pragma unroll
    for (int dx = 0; dx < 3; ++dx) {
      int x = ox * 8 - 2 + dx * 2;
      if ((unsigned)x >= 256u) continue;
      acc += w[c * 9 + dy * 3 + dx] * b2f(ip[((size_t)(y + 1) * IW + (x + 1)) * CH + c]);
    }
  }
  out[((size_t)(n * CH + c) << 10) + oy * 32 + ox] = acc;
}

// ---- per-8x8-block iDCT on planar f32 32x32 ------------------------------
__global__ __launch_bounds__(256)
void idct8_k(const float* __restrict__ in, float* __restrict__ out)
{
  __shared__ float ctab[8];
  if (threadIdx.x < 8) {
    const float c_[8] = {1.f, 0.70710678118654752f, 0.f, -0.70710678118654752f,
                         -1.f, -0.70710678118654752f, 0.f, 0.70710678118654752f};
    ctab[threadIdx.x] = c_[threadIdx.x];
  }
  __syncthreads();
  int idx = blockIdx.x * 256 + threadIdx.x;
  if (idx >= 8 * CH * 32 * 32) return;
  int ox = idx & 31, oy = (idx >> 5) & 31, bc = idx >> 10;
  int k = oy & 7, lq = ox & 7;
  const float* ip = in + bc * 1024 + (oy & ~7) * 32 + (ox & ~7);
  float acc = 0.f;
  #pragma unroll
  for (int mm = 0; mm < 8; ++mm) {
    float rk = ctab[(k * mm) & 7];
    float s = 0.f;
    #pragma unroll
    for (int nn = 0; nn < 8; ++nn)
      s += ctab[(lq * nn) & 7] * ip[mm * 32 + nn];
    acc += rk * s;
  }
  out[idx] = acc * 0.125f;
}

// ---- 1x1 conv + sigmoid + bilinear(32->256) multiply; cl bf16 in/out -----
__global__ __launch_bounds__(256)
void wgtmul_k(const u16* __restrict__ t1cl, const float* __restrict__ w3,
              const float* __restrict__ b3, const float* __restrict__ dct,
              u16* __restrict__ outcl)
{
  __shared__ float s_w[1600];
  __shared__ float s_b[40];
  int tid = threadIdx.x;
  for (int i = tid; i < 1600; i += 256) s_w[i] = w3[i];
  if (tid < 40) s_b[tid] = b3[tid];
  __syncthreads();
  int g = tid >> 6, l = tid & 63;
  int ocb = g * 10;
  int pix = blockIdx.x * 256 + l * 4;
  int n = pix >> 16;
  int y = (pix >> 8) & 255;
  int x = pix & 255;

  // load 4 px x 40 ic, keep packed bf16 pairs
  u32 xw[4][20];
  const u16* tp = t1cl + (size_t)n * IMG_CL + ((size_t)(y + 1) * IW + (x + 1)) * CH;
  #pragma unroll
  for (int j = 0; j < 4; ++j) {
    #pragma unroll
    for (int q = 0; q < 5; ++q) {
      uint4 v = *(const uint4*)(tp + j * CH + q * 8);
      xw[j][q * 4 + 0] = v.x; xw[j][q * 4 + 1] = v.y;
      xw[j][q * 4 + 2] = v.z; xw[j][q * 4 + 3] = v.w;
    }
  }

  float acc[10][4];
  #pragma unroll
  for (int o = 0; o < 10; ++o) {
    float bv = s_b[ocb + o];
    #pragma unroll
    for (int j = 0; j < 4; ++j) acc[o][j] = bv;
  }
  for (int ip = 0; ip < 20; ++ip) {        // ic pairs
    float xv0[4], xv1[4];
    #pragma unroll
    for (int j = 0; j < 4; ++j) { xv0[j] = lo16(xw[j][ip]); xv1[j] = hi16(xw[j][ip]); }
    #pragma unroll
    for (int o = 0; o < 10; ++o) {
      float w0 = s_w[(ocb + o) * 40 + 2 * ip];
      float w1 = s_w[(ocb + o) * 40 + 2 * ip + 1];
      #pragma unroll
      for (int j = 0; j < 4; ++j) acc[o][j] += w0 * xv0[j] + w1 * xv1[j];
    }
  }

  float sy = (y + 0.5f) * 0.125f - 0.5f;
  int y0 = (int)floorf(sy);
  float fy = sy - (float)y0;
  int y0c = max(y0, 0), y1c = min(y0 + 1, 31);
  int x0c[4], x1c[4]; float fx[4];
  #pragma unroll
  for (int j = 0; j < 4; ++j) {
    float sx = (x + j + 0.5f) * 0.125f - 0.5f;
    int xq = (int)floorf(sx);
    fx[j] = sx - (float)xq;
    x0c[j] = max(xq, 0); x1c[j] = min(xq + 1, 31);
  }
  u16* op = outcl + (size_t)n * IMG_CL + ((size_t)(y + 1) * IW + (x + 1)) * CH + ocb;
  u16 res[4][10];
  #pragma unroll
  for (int o = 0; o < 10; ++o) {
    int oc = ocb + o;
    const float* sp = dct + ((size_t)(n * CH + oc) << 10);
    const float* r0 = sp + y0c * 32;
    const float* r1 = sp + y1c * 32;
    #pragma unroll
    for (int j = 0; j < 4; ++j) {
      float wgt = 1.f / (1.f + expf(-acc[o][j]));
      float v00 = r0[x0c[j]], v01 = r0[x1c[j]];
      float v10 = r1[x0c[j]], v11 = r1[x1c[j]];
      float bil = (1.f - fy) * ((1.f - fx[j]) * v00 + fx[j] * v01)
                +         fy * ((1.f - fx[j]) * v10 + fx[j] * v11);
      res[j][o] = f2b(wgt * bil);
    }
  }
  #pragma unroll
  for (int j = 0; j < 4; ++j) {
    #pragma unroll
    for (int q = 0; q < 5; ++q) {
      u32 pk = (u32)res[j][2 * q] | ((u32)res[j][2 * q + 1] << 16);
      *(u32*)(op + (size_t)j * CH + 2 * q) = pk;
    }
  }
}

extern "C" void kernel_launch(void* const* d_in, const int* in_sizes, int n_in,
                              void* d_out, int out_size, void* d_ws, size_t ws_size,
                              hipStream_t stream)
{
  const float* x       = (const float*)d_in[0];
  const float* conv_w  = (const float*)d_in[1];
  const float* conv_b  = (const float*)d_in[2];
  const float* ddct_w  = (const float*)d_in[3];
  const float* ddct_b  = (const float*)d_in[4];
  const float* dctc_w  = (const float*)d_in[5];
  const float* dctc_b  = (const float*)d_in[6];
  const float* w1_w    = (const float*)d_in[7];
  const float* w1_b    = (const float*)d_in[8];
  const float* w3_w    = (const float*)d_in[9];
  const float* w3_b    = (const float*)d_in[10];
  const float* after_w = (const float*)d_in[11];
  const float* after_b = (const float*)d_in[12];

  char* ws = (char*)d_ws;
  const size_t CLB = (size_t)8 * IMG_CL * 2;          // 42,600,960 B
  u16*   xcl    = (u16*)ws;
  u16*   cl_a   = (u16*)(ws + CLB);
  u16*   cl_b   = (u16*)(ws + 2 * CLB);
  float* small0 = (float*)(ws + 3 * CLB);             // 1,310,720 B
  float* small1 = (float*)(ws + 3 * CLB + 1310720);   // 1,310,720 B
  u16*   wt     = (u16*)(ws + 3 * CLB + 2621440);     // 147,456 B

  // 0. weight transform (4 sets) + input cl conversion + ring zeroing
  prep_w_k<<<288, 256, 0, stream>>>(conv_w, ddct_w, w1_w, after_w, wt);
  prep_x_k<<<8 * IW, 256, 0, stream>>>(x, xcl, cl_a, cl_b);
  // 1. dct_feat = gelu(conv(x))                    -> cl_a
  convm_k<1, false, false><<<2048, 256, 0, stream>>>(xcl, wt, conv_b, nullptr, cl_a);
  // 2. dd = gelu(conv(dct_feat)) + dct_feat        -> cl_b
  convm_k<1, true, false><<<2048, 256, 0, stream>>>(cl_a, wt + WT_SET, ddct_b, cl_a, cl_b);
  // 3. depthwise strided conv                      -> small0
  dwconv_k<<<1280, 256, 0, stream>>>(cl_b, dctc_w, dctc_b, small0);
  // 4. per-block 8x8 iDCT                          -> small1
  idct8_k<<<1280, 256, 0, stream>>>(small0, small1);
  // 5. t1 = relu(conv(x, w1))                      -> cl_b (dd dead)
  convm_k<2, false, false><<<2048, 256, 0, stream>>>(xcl, wt + 2 * WT_SET, w1_b, nullptr, cl_b);
  // 6. prod = sigmoid(1x1(t1)) * bilinear(idct)    -> cl_a (dct_feat dead)
  wgtmul_k<<<2048, 256, 0, stream>>>(cl_b, w3_w, w3_b, small1, cl_a);
  // 7. out = conv(prod, after)                     -> d_out fp32 planar
  convm_k<0, false, true><<<2048, 256, 0, stream>>>(cl_a, wt + 3 * WT_SET, after_b, nullptr, (void*)d_out);
}

// Round 4
// 332.077 us; speedup vs baseline: 3.5911x; 1.1358x over previous
//
#include <hip/hip_runtime.h>

typedef unsigned short u16;
typedef unsigned int u32;
typedef __attribute__((ext_vector_type(8))) short bf16x8;
typedef __attribute__((ext_vector_type(4))) float f32x4;

#define CH 40
#define IW 258                   // ring-padded width (256 + 2)
#define IMG_CL (IW * IW * CH)    // u16 elements per image, channel-last padded
#define WT_SET (48 * 384)        // u16 per weight set

__device__ __forceinline__ float b2f(u16 u) {
  union { u32 i; float f; } v; v.i = ((u32)u) << 16; return v.f;
}
__device__ __forceinline__ u16 f2b(float f) {
  union { float f; u32 i; } v; v.f = f;
  u32 r = v.i + 0x7fffu + ((v.i >> 16) & 1u);
  return (u16)(r >> 16);
}

// ---- weights -> Wt bf16 [48][384] per set --------------------------------
// sets 0..3: 3x3 convs, k = dy*128 + dx*40 + ic ; set 4: w3 1x1, k = ic (pad)
__global__ __launch_bounds__(256)
void prep_w_k(const float* __restrict__ w0, const float* __restrict__ w1,
              const float* __restrict__ w2, const float* __restrict__ w3,
              const float* __restrict__ w4, u16* __restrict__ wt)
{
  int i = blockIdx.x * 256 + threadIdx.x;      // 5*48*384 = 92160
  if (i >= 5 * WT_SET) return;
  int k = i % 384;
  int oc = (i / 384) % 48;
  int set = i / WT_SET;
  u16 v = 0;
  if (set == 4) {
    if (oc < 40 && k < 40) v = f2b(w4[oc * 40 + k]);
  } else {
    int dy = k >> 7;
    int r = k & 127;
    if (oc < 40 && r < 120) {
      int dx = r / 40;
      int ic = r - dx * 40;
      const float* w = (set == 0) ? w0 : (set == 1) ? w1 : (set == 2) ? w2 : w3;
      v = f2b(w[((oc * 40 + ic) * 3 + dy) * 3 + dx]);
    }
  }
  wt[i] = v;
}

// ---- x fp32 planar -> xcl bf16 channel-last + zero rings of all 3 cl bufs
__global__ __launch_bounds__(256)
void prep_x_k(const float* __restrict__ x, u16* __restrict__ xcl,
              u16* __restrict__ cla, u16* __restrict__ clb)
{
  const int n = blockIdx.x / IW;
  const int yr = blockIdx.x % IW;          // padded row 0..257
  const int t = threadIdx.x;
  const size_t base = (size_t)n * IMG_CL + (size_t)yr * (IW * CH);
  const uint4 z = {0u, 0u, 0u, 0u};

  if (yr == 0 || yr == IW - 1) {           // full ring row
    for (int i = t; i < (IW * CH) / 8; i += 256) {
      ((uint4*)(xcl + base))[i] = z;
      ((uint4*)(cla + base))[i] = z;
      ((uint4*)(clb + base))[i] = z;
    }
    return;
  }
  if (t < 5) {                             // left ring col (40 u16 = 5 x 16B)
    ((uint4*)(xcl + base))[t] = z;
    ((uint4*)(cla + base))[t] = z;
    ((uint4*)(clb + base))[t] = z;
  } else if (t < 10) {                     // right ring col
    size_t b2 = base + (size_t)(IW - 1) * CH;
    ((uint4*)(xcl + b2))[t - 5] = z;
    ((uint4*)(cla + b2))[t - 5] = z;
    ((uint4*)(clb + b2))[t - 5] = z;
  }
  const int y = yr - 1;
  const float* xp = x + (size_t)n * CH * 65536 + (size_t)y * 256 + t;
  __attribute__((aligned(16))) u16 buf[40];
  #pragma unroll
  for (int ic = 0; ic < 40; ++ic) buf[ic] = f2b(xp[(size_t)ic * 65536]);
  u16* dst = xcl + base + (size_t)(t + 1) * CH;
  #pragma unroll
  for (int q = 0; q < 5; ++q) ((uint4*)dst)[q] = ((const uint4*)buf)[q];
}

// ---- MFMA implicit-GEMM conv 3x3 pad 1, cl bf16 in, cl bf16 / planar f32 out
template<int ACT, bool RES, bool PLANAR_OUT>
__global__ __launch_bounds__(256)
void convm_k(const u16* __restrict__ incl, const u16* __restrict__ wt,
             const float* __restrict__ bias, const u16* __restrict__ rescl,
             void* __restrict__ outp)
{
  __shared__ u16 s_in[6 * 66 * CH];        // 15840 u16 = 31680 B

  const int tid = threadIdx.x;
  const int bid = blockIdx.x;
  const int n = bid >> 8;
  const int tb = bid & 255;
  const int y0 = (tb >> 2) << 2;           // 64 y-tiles of 4 rows
  const int x0 = (tb & 3) << 6;            // 4 x-tiles of 64 px

  const u16* src = incl + (size_t)n * IMG_CL + ((size_t)y0 * IW + x0) * CH;
  for (int i = tid; i < 1980; i += 256) {  // 6 rows x 330 chunks of 16B
    int r = i / 330;
    int o = i - r * 330;
    uint4 v = *(const uint4*)(src + (size_t)r * (IW * CH) + o * 8);
    *(uint4*)(s_in + r * (66 * CH) + o * 8) = v;
  }
  __syncthreads();

  const int w = tid >> 6;                  // wave -> output row y0+w
  const int l = tid & 63;
  const int g = l >> 4;                    // lane group 0..3
  const int m = l & 15;

  f32x4 acc[4][3];
  #pragma unroll
  for (int xt = 0; xt < 4; ++xt)
    #pragma unroll
    for (int t = 0; t < 3; ++t) acc[xt][t] = (f32x4){0.f, 0.f, 0.f, 0.f};

  #pragma unroll
  for (int s = 0; s < 12; ++s) {
    const int dy = s >> 2;
    const int c = ((s & 3) << 2) + g;      // k-chunk id 0..15
    int dx, icb;
    if (c >= 15)      { dx = 0; icb = 0; }     // zero-weight pad chunk
    else if (c >= 10) { dx = 2; icb = (c - 10) * 8; }
    else if (c >= 5)  { dx = 1; icb = (c - 5) * 8; }
    else              { dx = 0; icb = c * 8; }

    const int abase = (w + dy) * (66 * CH) + (m + dx) * CH + icb;
    bf16x8 a0 = *(const bf16x8*)(s_in + abase);
    bf16x8 a1 = *(const bf16x8*)(s_in + abase + 16 * CH);
    bf16x8 a2 = *(const bf16x8*)(s_in + abase + 32 * CH);
    bf16x8 a3 = *(const bf16x8*)(s_in + abase + 48 * CH);

    const int wb = s * 32 + g * 8;
    bf16x8 b0 = *(const bf16x8*)(wt + (m     ) * 384 + wb);
    bf16x8 b1 = *(const bf16x8*)(wt + (m + 16) * 384 + wb);
    bf16x8 b2 = *(const bf16x8*)(wt + (m + 32) * 384 + wb);

    acc[0][0] = __builtin_amdgcn_mfma_f32_16x16x32_bf16(a0, b0, acc[0][0], 0, 0, 0);
    acc[1][0] = __builtin_amdgcn_mfma_f32_16x16x32_bf16(a1, b0, acc[1][0], 0, 0, 0);
    acc[2][0] = __builtin_amdgcn_mfma_f32_16x16x32_bf16(a2, b0, acc[2][0], 0, 0, 0);
    acc[3][0] = __builtin_amdgcn_mfma_f32_16x16x32_bf16(a3, b0, acc[3][0], 0, 0, 0);
    acc[0][1] = __builtin_amdgcn_mfma_f32_16x16x32_bf16(a0, b1, acc[0][1], 0, 0, 0);
    acc[1][1] = __builtin_amdgcn_mfma_f32_16x16x32_bf16(a1, b1, acc[1][1], 0, 0, 0);
    acc[2][1] = __builtin_amdgcn_mfma_f32_16x16x32_bf16(a2, b1, acc[2][1], 0, 0, 0);
    acc[3][1] = __builtin_amdgcn_mfma_f32_16x16x32_bf16(a3, b1, acc[3][1], 0, 0, 0);
    acc[0][2] = __builtin_amdgcn_mfma_f32_16x16x32_bf16(a0, b2, acc[0][2], 0, 0, 0);
    acc[1][2] = __builtin_amdgcn_mfma_f32_16x16x32_bf16(a1, b2, acc[1][2], 0, 0, 0);
    acc[2][2] = __builtin_amdgcn_mfma_f32_16x16x32_bf16(a2, b2, acc[2][2], 0, 0, 0);
    acc[3][2] = __builtin_amdgcn_mfma_f32_16x16x32_bf16(a3, b2, acc[3][2], 0, 0, 0);
  }

  const int y = y0 + w;
  const float bv0 = bias[m];
  const float bv1 = bias[m + 16];
  const float bv2 = (m < 8) ? bias[m + 32] : 0.f;

  #pragma unroll
  for (int t = 0; t < 3; ++t) {
    const int oc = m + 16 * t;
    if (t == 2 && m >= 8) continue;        // oc >= 40: padding
    const float bv = (t == 0) ? bv0 : (t == 1) ? bv1 : bv2;
    #pragma unroll
    for (int xt = 0; xt < 4; ++xt) {
      const int xb = x0 + xt * 16 + 4 * g;
      float v[4];
      #pragma unroll
      for (int i = 0; i < 4; ++i) {
        float tv = acc[xt][t][i] + bv;
        if (ACT == 1) tv = 0.5f * tv * (1.f + erff(tv * 0.70710678118654752f));
        else if (ACT == 2) tv = fmaxf(tv, 0.f);
        v[i] = tv;
      }
      if (RES) {
        const u16* rp = rescl + (size_t)n * IMG_CL + ((size_t)(y + 1) * IW + (xb + 1)) * CH + oc;
        #pragma unroll
        for (int i = 0; i < 4; ++i) v[i] += b2f(rp[(size_t)i * CH]);
      }
      if (PLANAR_OUT) {
        float4 st = make_float4(v[0], v[1], v[2], v[3]);
        *(float4*)((float*)outp + (((size_t)(n * CH + oc)) << 16) + ((size_t)y << 8) + xb) = st;
      } else {
        u16* op = (u16*)outp + (size_t)n * IMG_CL + ((size_t)(y + 1) * IW + (xb + 1)) * CH + oc;
        #pragma unroll
        for (int i = 0; i < 4; ++i) op[(size_t)i * CH] = f2b(v[i]);
      }
    }
  }
}

// ---- depthwise conv k3 s8 p2 d2 on cl bf16 -> planar f32 (8,40,32,32) ----
__global__ __launch_bounds__(256)
void dwconv_k(const u16* __restrict__ incl, const float* __restrict__ w,
              const float* __restrict__ b, float* __restrict__ out)
{
  int idx = blockIdx.x * 256 + threadIdx.x;
  if (idx >= 8 * 32 * 32 * CH) return;
  int c = idx % CH;
  int p = idx / CH;
  int ox = p & 31;
  int oy = (p >> 5) & 31;
  int n = p >> 10;
  float acc = b[c];
  const u16* ip = incl + (size_t)n * IMG_CL;
  #pragma unroll
  for (int dy = 0; dy < 3; ++dy) {
    int y = oy * 8 - 2 + dy * 2;
    if ((unsigned)y >= 256u) continue;
    #pragma unroll
    for (int dx = 0; dx < 3; ++dx) {
      int x = ox * 8 - 2 + dx * 2;
      if ((unsigned)x >= 256u) continue;
      acc += w[c * 9 + dy * 3 + dx] * b2f(ip[((size_t)(y + 1) * IW + (x + 1)) * CH + c]);
    }
  }
  out[((size_t)(n * CH + c) << 10) + oy * 32 + ox] = acc;
}

// ---- per-8x8-block iDCT on planar f32 32x32 ------------------------------
__global__ __launch_bounds__(256)
void idct8_k(const float* __restrict__ in, float* __restrict__ out)
{
  __shared__ float ctab[8];
  if (threadIdx.x < 8) {
    const float c_[8] = {1.f, 0.70710678118654752f, 0.f, -0.70710678118654752f,
                         -1.f, -0.70710678118654752f, 0.f, 0.70710678118654752f};
    ctab[threadIdx.x] = c_[threadIdx.x];
  }
  __syncthreads();
  int idx = blockIdx.x * 256 + threadIdx.x;
  if (idx >= 8 * CH * 32 * 32) return;
  int ox = idx & 31, oy = (idx >> 5) & 31, bc = idx >> 10;
  int k = oy & 7, lq = ox & 7;
  const float* ip = in + bc * 1024 + (oy & ~7) * 32 + (ox & ~7);
  float acc = 0.f;
  #pragma unroll
  for (int mm = 0; mm < 8; ++mm) {
    float rk = ctab[(k * mm) & 7];
    float s = 0.f;
    #pragma unroll
    for (int nn = 0; nn < 8; ++nn)
      s += ctab[(lq * nn) & 7] * ip[mm * 32 + nn];
    acc += rk * s;
  }
  out[idx] = acc * 0.125f;
}

// ---- MFMA 1x1 conv + sigmoid + bilinear(32->256) multiply; cl bf16 -------
// block = (n, row y); 4 waves cover x 0..255, all 40 oc
__global__ __launch_bounds__(256)
void wgtmul_k(const u16* __restrict__ t1cl, const u16* __restrict__ wt3,
              const float* __restrict__ b3, const float* __restrict__ dct,
              u16* __restrict__ outcl)
{
  __shared__ float s_yw[40 * 33];          // y-interpolated dct rows (padded)

  const int bid = blockIdx.x;
  const int n = bid >> 8;
  const int y = bid & 255;
  const int tid = threadIdx.x;

  float sy = (y + 0.5f) * 0.125f - 0.5f;
  float yq = floorf(sy);
  float fy = sy - yq;
  int y0c = max((int)yq, 0), y1c = min((int)yq + 1, 31);

  for (int i = tid; i < 1280; i += 256) {
    int oc = i >> 5, c = i & 31;
    const float* sp = dct + ((size_t)(n * CH + oc) << 10);
    s_yw[oc * 33 + c] = (1.f - fy) * sp[y0c * 32 + c] + fy * sp[y1c * 32 + c];
  }
  __syncthreads();

  const int w = tid >> 6;
  const int l = tid & 63;
  const int g = l >> 4;
  const int m = l & 15;
  const int xb = w << 6;                   // wave covers 64 px

  const u16* tp = t1cl + (size_t)n * IMG_CL + ((size_t)(y + 1) * IW + 1) * CH;

  f32x4 acc[4][3];
  #pragma unroll
  for (int xt = 0; xt < 4; ++xt)
    #pragma unroll
    for (int t = 0; t < 3; ++t) acc[xt][t] = (f32x4){0.f, 0.f, 0.f, 0.f};

  #pragma unroll
  for (int xt = 0; xt < 4; ++xt) {
    const u16* ap = tp + (size_t)(xb + xt * 16 + m) * CH;
    bf16x8 a0 = *(const bf16x8*)(ap + 8 * g);         // k = 8g..8g+7 (ic 0..31)
    bf16x8 a1 = *(const bf16x8*)(ap + 32 + 8 * g);    // k = 32+8g (g>0: garbage*0)
    #pragma unroll
    for (int t = 0; t < 3; ++t) {
      bf16x8 b0 = *(const bf16x8*)(wt3 + (m + 16 * t) * 384 + 8 * g);
      bf16x8 b1 = *(const bf16x8*)(wt3 + (m + 16 * t) * 384 + 32 + 8 * g);
      acc[xt][t] = __builtin_amdgcn_mfma_f32_16x16x32_bf16(a0, b0, acc[xt][t], 0, 0, 0);
      acc[xt][t] = __builtin_amdgcn_mfma_f32_16x16x32_bf16(a1, b1, acc[xt][t], 0, 0, 0);
    }
  }

  u16* op = outcl + (size_t)n * IMG_CL + ((size_t)(y + 1) * IW + 1) * CH;
  #pragma unroll
  for (int t = 0; t < 3; ++t) {
    const int oc = m + 16 * t;
    if (t == 2 && m >= 8) continue;
    const float bv = b3[oc];
    const float* yw = &s_yw[oc * 33];
    #pragma unroll
    for (int xt = 0; xt < 4; ++xt) {
      #pragma unroll
      for (int i = 0; i < 4; ++i) {
        int px = xb + xt * 16 + 4 * g + i;
        float wgt = 1.f / (1.f + expf(-(acc[xt][t][i] + bv)));
        float sx = (px + 0.5f) * 0.125f - 0.5f;
        float xq = floorf(sx);
        float fx = sx - xq;
        int x0c = max((int)xq, 0), x1c = min((int)xq + 1, 31);
        float bil = (1.f - fx) * yw[x0c] + fx * yw[x1c];
        op[(size_t)px * CH + oc] = f2b(wgt * bil);
      }
    }
  }
}

extern "C" void kernel_launch(void* const* d_in, const int* in_sizes, int n_in,
                              void* d_out, int out_size, void* d_ws, size_t ws_size,
                              hipStream_t stream)
{
  const float* x       = (const float*)d_in[0];
  const float* conv_w  = (const float*)d_in[1];
  const float* conv_b  = (const float*)d_in[2];
  const float* ddct_w  = (const float*)d_in[3];
  const float* ddct_b  = (const float*)d_in[4];
  const float* dctc_w  = (const float*)d_in[5];
  const float* dctc_b  = (const float*)d_in[6];
  const float* w1_w    = (const float*)d_in[7];
  const float* w1_b    = (const float*)d_in[8];
  const float* w3_w    = (const float*)d_in[9];
  const float* w3_b    = (const float*)d_in[10];
  const float* after_w = (const float*)d_in[11];
  const float* after_b = (const float*)d_in[12];

  char* ws = (char*)d_ws;
  const size_t CLB = (size_t)8 * IMG_CL * 2;          // 42,600,960 B
  u16*   xcl    = (u16*)ws;
  u16*   cl_a   = (u16*)(ws + CLB);
  u16*   cl_b   = (u16*)(ws + 2 * CLB);
  float* small0 = (float*)(ws + 3 * CLB);             // 1,310,720 B
  float* small1 = (float*)(ws + 3 * CLB + 1310720);   // 1,310,720 B
  u16*   wt     = (u16*)(ws + 3 * CLB + 2621440);     // 184,320 B (5 sets)

  // 0. weight transform (5 sets) + input cl conversion + ring zeroing
  prep_w_k<<<360, 256, 0, stream>>>(conv_w, ddct_w, w1_w, after_w, w3_w, wt);
  prep_x_k<<<8 * IW, 256, 0, stream>>>(x, xcl, cl_a, cl_b);
  // 1. dct_feat = gelu(conv(x))                    -> cl_a
  convm_k<1, false, false><<<2048, 256, 0, stream>>>(xcl, wt, conv_b, nullptr, cl_a);
  // 2. dd = gelu(conv(dct_feat)) + dct_feat        -> cl_b
  convm_k<1, true, false><<<2048, 256, 0, stream>>>(cl_a, wt + WT_SET, ddct_b, cl_a, cl_b);
  // 3. depthwise strided conv                      -> small0
  dwconv_k<<<1280, 256, 0, stream>>>(cl_b, dctc_w, dctc_b, small0);
  // 4. per-block 8x8 iDCT                          -> small1
  idct8_k<<<1280, 256, 0, stream>>>(small0, small1);
  // 5. t1 = relu(conv(x, w1))                      -> cl_b (dd dead)
  convm_k<2, false, false><<<2048, 256, 0, stream>>>(xcl, wt + 2 * WT_SET, w1_b, nullptr, cl_b);
  // 6. prod = sigmoid(1x1(t1)) * bilinear(idct)    -> cl_a (dct_feat dead)
  wgtmul_k<<<2048, 256, 0, stream>>>(cl_b, wt + 4 * WT_SET, w3_b, small1, cl_a);
  // 7. out = conv(prod, after)                     -> d_out fp32 planar
  convm_k<0, false, true><<<2048, 256, 0, stream>>>(cl_a, wt + 3 * WT_SET, after_b, nullptr, (void*)d_out);
}

// Round 5
// 330.329 us; speedup vs baseline: 3.6101x; 1.0053x over previous
//
#include <hip/hip_runtime.h>

typedef unsigned short u16;
typedef unsigned int u32;
typedef __attribute__((ext_vector_type(8))) short bf16x8;
typedef __attribute__((ext_vector_type(4))) float f32x4;

#define CH 40
#define IW 258                   // ring-padded width (256 + 2)
#define IMG_CL (IW * IW * CH)    // u16 elements per image, channel-last padded
#define WT_SET (48 * 384)        // u16 per weight set

__device__ __forceinline__ float b2f(u16 u) {
  union { u32 i; float f; } v; v.i = ((u32)u) << 16; return v.f;
}
__device__ __forceinline__ u16 f2b(float f) {
  union { float f; u32 i; } v; v.f = f;
  u32 r = v.i + 0x7fffu + ((v.i >> 16) & 1u);
  return (u16)(r >> 16);
}
// add two packed bf16 pairs in fp32, repack
__device__ __forceinline__ u32 addbf2(u32 a, u32 b) {
  union { u32 i; float f; } lo_a, lo_b, hi_a, hi_b;
  lo_a.i = a << 16; lo_b.i = b << 16;
  hi_a.i = a & 0xffff0000u; hi_b.i = b & 0xffff0000u;
  float lo = lo_a.f + lo_b.f, hi = hi_a.f + hi_b.f;
  return (u32)f2b(lo) | ((u32)f2b(hi) << 16);
}

// ---- weights -> Wt bf16 [48][384] per set --------------------------------
// sets 0..3: 3x3 convs, k = dy*128 + dx*40 + ic ; set 4: w3 1x1, k = ic (pad)
__global__ __launch_bounds__(256)
void prep_w_k(const float* __restrict__ w0, const float* __restrict__ w1,
              const float* __restrict__ w2, const float* __restrict__ w3,
              const float* __restrict__ w4, u16* __restrict__ wt)
{
  int i = blockIdx.x * 256 + threadIdx.x;      // 5*48*384 = 92160
  if (i >= 5 * WT_SET) return;
  int k = i % 384;
  int oc = (i / 384) % 48;
  int set = i / WT_SET;
  u16 v = 0;
  if (set == 4) {
    if (oc < 40 && k < 40) v = f2b(w4[oc * 40 + k]);
  } else {
    int dy = k >> 7;
    int r = k & 127;
    if (oc < 40 && r < 120) {
      int dx = r / 40;
      int ic = r - dx * 40;
      const float* w = (set == 0) ? w0 : (set == 1) ? w1 : (set == 2) ? w2 : w3;
      v = f2b(w[((oc * 40 + ic) * 3 + dy) * 3 + dx]);
    }
  }
  wt[i] = v;
}

// ---- x fp32 planar -> xcl bf16 channel-last + zero rings of all 3 cl bufs
__global__ __launch_bounds__(256)
void prep_x_k(const float* __restrict__ x, u16* __restrict__ xcl,
              u16* __restrict__ cla, u16* __restrict__ clb)
{
  const int n = blockIdx.x / IW;
  const int yr = blockIdx.x % IW;          // padded row 0..257
  const int t = threadIdx.x;
  const size_t base = (size_t)n * IMG_CL + (size_t)yr * (IW * CH);
  const uint4 z = {0u, 0u, 0u, 0u};

  if (yr == 0 || yr == IW - 1) {           // full ring row
    for (int i = t; i < (IW * CH) / 8; i += 256) {
      ((uint4*)(xcl + base))[i] = z;
      ((uint4*)(cla + base))[i] = z;
      ((uint4*)(clb + base))[i] = z;
    }
    return;
  }
  if (t < 5) {                             // left ring col (40 u16 = 5 x 16B)
    ((uint4*)(xcl + base))[t] = z;
    ((uint4*)(cla + base))[t] = z;
    ((uint4*)(clb + base))[t] = z;
  } else if (t < 10) {                     // right ring col
    size_t b2 = base + (size_t)(IW - 1) * CH;
    ((uint4*)(xcl + b2))[t - 5] = z;
    ((uint4*)(cla + b2))[t - 5] = z;
    ((uint4*)(clb + b2))[t - 5] = z;
  }
  const int y = yr - 1;
  const float* xp = x + (size_t)n * CH * 65536 + (size_t)y * 256 + t;
  __attribute__((aligned(16))) u16 buf[40];
  #pragma unroll
  for (int ic = 0; ic < 40; ++ic) buf[ic] = f2b(xp[(size_t)ic * 65536]);
  u16* dst = xcl + base + (size_t)(t + 1) * CH;
  #pragma unroll
  for (int q = 0; q < 5; ++q) ((uint4*)dst)[q] = ((const uint4*)buf)[q];
}

// ---- MFMA implicit-GEMM conv 3x3 pad 1, cl bf16 in -----------------------
// cl out (PLANAR_OUT=false): swapped operands, LDS-restaged coalesced stores
// planar f32 out (PLANAR_OUT=true): unswapped, direct float4 stores
template<int ACT, bool RES, bool PLANAR_OUT>
__global__ __launch_bounds__(256, 4)
void convm_k(const u16* __restrict__ incl, const u16* __restrict__ wt,
             const float* __restrict__ bias, const u16* __restrict__ rescl,
             void* __restrict__ outp)
{
  __shared__ u16 s_in[6 * 66 * CH];        // 31680 B; reused as 4x6144B out-stage

  const int tid = threadIdx.x;
  const int bid = blockIdx.x;
  const int n = bid >> 8;
  const int tb = bid & 255;
  const int y0 = (tb >> 2) << 2;           // 64 y-tiles of 4 rows
  const int x0 = (tb & 3) << 6;            // 4 x-tiles of 64 px

  const u16* src = incl + (size_t)n * IMG_CL + ((size_t)y0 * IW + x0) * CH;
  for (int i = tid; i < 1980; i += 256) {  // 6 rows x 330 chunks of 16B, LDS-linear
    int r = i / 330;
    int o = i - r * 330;
    uint4 v = *(const uint4*)(src + (size_t)r * (IW * CH) + o * 8);
    *(uint4*)(s_in + i * 8) = v;
  }
  __syncthreads();

  const int w = tid >> 6;                  // wave -> output row y0+w
  const int l = tid & 63;
  const int g = l >> 4;                    // lane k-chunk group 0..3
  const int m = l & 15;

  f32x4 acc[4][3];
  #pragma unroll
  for (int xt = 0; xt < 4; ++xt)
    #pragma unroll
    for (int t = 0; t < 3; ++t) acc[xt][t] = (f32x4){0.f, 0.f, 0.f, 0.f};

  bf16x8 aC[4], bC[3], aN[4], bN[3];

  auto lf = [&](int s, bf16x8* A, bf16x8* B) {
    const int dy = s >> 2;
    const int c = ((s & 3) << 2) + g;      // k-chunk id 0..15
    int dx, icb;
    if (c >= 15)      { dx = 0; icb = 0; }     // zero-weight pad chunk
    else if (c >= 10) { dx = 2; icb = (c - 10) * 8; }
    else if (c >= 5)  { dx = 1; icb = (c - 5) * 8; }
    else              { dx = 0; icb = c * 8; }
    const int abase = (w + dy) * (66 * CH) + (m + dx) * CH + icb;
    A[0] = *(const bf16x8*)(s_in + abase);
    A[1] = *(const bf16x8*)(s_in + abase + 16 * CH);
    A[2] = *(const bf16x8*)(s_in + abase + 32 * CH);
    A[3] = *(const bf16x8*)(s_in + abase + 48 * CH);
    const int wb = s * 32 + g * 8;
    B[0] = *(const bf16x8*)(wt + m * 384 + wb);
    B[1] = *(const bf16x8*)(wt + (m + 16) * 384 + wb);
    B[2] = *(const bf16x8*)(wt + (m + 32) * 384 + wb);
  };

  lf(0, aC, bC);
  #pragma unroll
  for (int s = 0; s < 12; ++s) {
    if (s < 11) lf(s + 1, aN, bN);         // prefetch next step (2-deep pipeline)
    #pragma unroll
    for (int t = 0; t < 3; ++t)
      #pragma unroll
      for (int xt = 0; xt < 4; ++xt)
        acc[xt][t] = PLANAR_OUT
          ? __builtin_amdgcn_mfma_f32_16x16x32_bf16(aC[xt], bC[t], acc[xt][t], 0, 0, 0)
          : __builtin_amdgcn_mfma_f32_16x16x32_bf16(bC[t], aC[xt], acc[xt][t], 0, 0, 0);
    if (s < 11) {
      #pragma unroll
      for (int q = 0; q < 4; ++q) aC[q] = aN[q];
      #pragma unroll
      for (int q = 0; q < 3; ++q) bC[q] = bN[q];
    }
  }

  const int y = y0 + w;

  if (PLANAR_OUT) {
    // D: row = px (4g+i), col = oc (m+16t)  -> direct float4 stores
    const float bv0 = bias[m];
    const float bv1 = bias[m + 16];
    const float bv2 = (m < 8) ? bias[m + 32] : 0.f;
    #pragma unroll
    for (int t = 0; t < 3; ++t) {
      const int oc = m + 16 * t;
      if (t == 2 && m >= 8) continue;
      const float bv = (t == 0) ? bv0 : (t == 1) ? bv1 : bv2;
      #pragma unroll
      for (int xt = 0; xt < 4; ++xt) {
        const int xb = x0 + xt * 16 + 4 * g;
        float v[4];
        #pragma unroll
        for (int i = 0; i < 4; ++i) {
          float tv = acc[xt][t][i] + bv;
          if (ACT == 1) tv = 0.5f * tv * (1.f + erff(tv * 0.70710678118654752f));
          else if (ACT == 2) tv = fmaxf(tv, 0.f);
          v[i] = tv;
        }
        *(float4*)((float*)outp + (((size_t)(n * CH + oc)) << 16) + ((size_t)y << 8) + xb)
            = make_float4(v[0], v[1], v[2], v[3]);
      }
    }
  } else {
    // D: row = oc (4g+i + 16t), col = px (m + 16xt) -> LDS restage, coalesced
    __syncthreads();                       // all K-loop s_in reads complete
    u16* s_out = s_in + w * 3072;          // per-wave 6144 B region
    float4 bv[3];
    bv[0] = *(const float4*)(bias + 4 * g);
    bv[1] = *(const float4*)(bias + 16 + 4 * g);
    bv[2] = (g < 2) ? *(const float4*)(bias + 32 + 4 * g)
                    : make_float4(0.f, 0.f, 0.f, 0.f);
    #pragma unroll
    for (int t = 0; t < 3; ++t) {
      if (t == 2 && g >= 2) continue;      // oc >= 40: padding
      #pragma unroll
      for (int xt = 0; xt < 4; ++xt) {
        const int pxl = xt * 16 + m;
        float v[4];
        #pragma unroll
        for (int i = 0; i < 4; ++i) {
          float tv = acc[xt][t][i] + ((const float*)&bv[t])[i];
          if (ACT == 1) tv = 0.5f * tv * (1.f + erff(tv * 0.70710678118654752f));
          else if (ACT == 2) tv = fmaxf(tv, 0.f);
          v[i] = tv;
        }
        uint2 pk;
        pk.x = (u32)f2b(v[0]) | ((u32)f2b(v[1]) << 16);
        pk.y = (u32)f2b(v[2]) | ((u32)f2b(v[3]) << 16);
        int byt = pxl * 80 + (16 * t + 4 * g) * 2;
        byt ^= ((pxl >> 3) & 7) << 4;      // XOR-swizzle keyed on px>>3
        *(uint2*)((char*)s_out + byt) = pk;
      }
    }
    // readback (lane l <-> px l) + coalesced 16B stores
    const size_t rowu = (size_t)n * IMG_CL + ((size_t)(y + 1) * IW + (x0 + 1)) * CH;
    #pragma unroll
    for (int q = 0; q < 5; ++q) {
      int byt = l * 80 + q * 16;
      byt ^= ((l >> 3) & 7) << 4;
      uint4 d = *(const uint4*)((const char*)s_out + byt);
      if (RES) {
        uint4 rv = *(const uint4*)(rescl + rowu + (size_t)l * 40 + q * 8);
        d.x = addbf2(d.x, rv.x); d.y = addbf2(d.y, rv.y);
        d.z = addbf2(d.z, rv.z); d.w = addbf2(d.w, rv.w);
      }
      *(uint4*)((u16*)outp + rowu + (size_t)l * 40 + q * 8) = d;
    }
  }
}

// ---- depthwise conv k3 s8 p2 d2 on cl bf16 -> planar f32 (8,40,32,32) ----
__global__ __launch_bounds__(256)
void dwconv_k(const u16* __restrict__ incl, const float* __restrict__ w,
              const float* __restrict__ b, float* __restrict__ out)
{
  int idx = blockIdx.x * 256 + threadIdx.x;
  if (idx >= 8 * 32 * 32 * CH) return;
  int c = idx % CH;
  int p = idx / CH;
  int ox = p & 31;
  int oy = (p >> 5) & 31;
  int n = p >> 10;
  float acc = b[c];
  const u16* ip = incl + (size_t)n * IMG_CL;
  #pragma unroll
  for (int dy = 0; dy < 3; ++dy) {
    int y = oy * 8 - 2 + dy * 2;
    if ((unsigned)y >= 256u) continue;
    #pragma unroll
    for (int dx = 0; dx < 3; ++dx) {
      int x = ox * 8 - 2 + dx * 2;
      if ((unsigned)x >= 256u) continue;
      acc += w[c * 9 + dy * 3 + dx] * b2f(ip[((size_t)(y + 1) * IW + (x + 1)) * CH + c]);
    }
  }
  out[((size_t)(n * CH + c) << 10) + oy * 32 + ox] = acc;
}

// ---- per-8x8-block iDCT on planar f32 32x32 ------------------------------
__global__ __launch_bounds__(256)
void idct8_k(const float* __restrict__ in, float* __restrict__ out)
{
  __shared__ float ctab[8];
  if (threadIdx.x < 8) {
    const float c_[8] = {1.f, 0.70710678118654752f, 0.f, -0.70710678118654752f,
                         -1.f, -0.70710678118654752f, 0.f, 0.70710678118654752f};
    ctab[threadIdx.x] = c_[threadIdx.x];
  }
  __syncthreads();
  int idx = blockIdx.x * 256 + threadIdx.x;
  if (idx >= 8 * CH * 32 * 32) return;
  int ox = idx & 31, oy = (idx >> 5) & 31, bc = idx >> 10;
  int k = oy & 7, lq = ox & 7;
  const float* ip = in + bc * 1024 + (oy & ~7) * 32 + (ox & ~7);
  float acc = 0.f;
  #pragma unroll
  for (int mm = 0; mm < 8; ++mm) {
    float rk = ctab[(k * mm) & 7];
    float s = 0.f;
    #pragma unroll
    for (int nn = 0; nn < 8; ++nn)
      s += ctab[(lq * nn) & 7] * ip[mm * 32 + nn];
    acc += rk * s;
  }
  out[idx] = acc * 0.125f;
}

// ---- MFMA 1x1 conv + sigmoid + bilinear(32->256) multiply; cl bf16 -------
// block = (n, row y); 4 waves cover x 0..255; swapped operands + LDS restage
__global__ __launch_bounds__(256)
void wgtmul_k(const u16* __restrict__ t1cl, const u16* __restrict__ wt3,
              const float* __restrict__ b3, const float* __restrict__ dct,
              u16* __restrict__ outcl)
{
  __shared__ float s_yw[40 * 33];          // y-interpolated dct rows (padded)
  __shared__ u16 s_out[4 * 3072];          // per-wave out-stage regions

  const int bid = blockIdx.x;
  const int n = bid >> 8;
  const int y = bid & 255;
  const int tid = threadIdx.x;

  float sy = (y + 0.5f) * 0.125f - 0.5f;
  float yq = floorf(sy);
  float fy = sy - yq;
  int y0c = max((int)yq, 0), y1c = min((int)yq + 1, 31);

  for (int i = tid; i < 1280; i += 256) {
    int oc = i >> 5, c = i & 31;
    const float* sp = dct + ((size_t)(n * CH + oc) << 10);
    s_yw[oc * 33 + c] = (1.f - fy) * sp[y0c * 32 + c] + fy * sp[y1c * 32 + c];
  }
  __syncthreads();

  const int w = tid >> 6;
  const int l = tid & 63;
  const int g = l >> 4;
  const int m = l & 15;
  const int xb = w << 6;                   // wave covers 64 px

  const u16* tp = t1cl + (size_t)n * IMG_CL + ((size_t)(y + 1) * IW + 1) * CH;

  f32x4 acc[4][3];
  #pragma unroll
  for (int xt = 0; xt < 4; ++xt)
    #pragma unroll
    for (int t = 0; t < 3; ++t) acc[xt][t] = (f32x4){0.f, 0.f, 0.f, 0.f};

  #pragma unroll
  for (int xt = 0; xt < 4; ++xt) {
    const u16* ap = tp + (size_t)(xb + xt * 16 + m) * CH;
    bf16x8 a0 = *(const bf16x8*)(ap + 8 * g);         // k = 8g..8g+7
    bf16x8 a1 = *(const bf16x8*)(ap + 32 + 8 * g);    // pad chunk (x0 weights)
    #pragma unroll
    for (int t = 0; t < 3; ++t) {
      bf16x8 b0 = *(const bf16x8*)(wt3 + (m + 16 * t) * 384 + 8 * g);
      bf16x8 b1 = *(const bf16x8*)(wt3 + (m + 16 * t) * 384 + 32 + 8 * g);
      acc[xt][t] = __builtin_amdgcn_mfma_f32_16x16x32_bf16(b0, a0, acc[xt][t], 0, 0, 0);
      acc[xt][t] = __builtin_amdgcn_mfma_f32_16x16x32_bf16(b1, a1, acc[xt][t], 0, 0, 0);
    }
  }

  // epilogue: lane holds px = xb+16xt+m, oc = 16t+4g+i
  u16* so = s_out + w * 3072;
  float4 bv[3];
  bv[0] = *(const float4*)(b3 + 4 * g);
  bv[1] = *(const float4*)(b3 + 16 + 4 * g);
  bv[2] = (g < 2) ? *(const float4*)(b3 + 32 + 4 * g) : make_float4(0.f, 0.f, 0.f, 0.f);
  #pragma unroll
  for (int t = 0; t < 3; ++t) {
    if (t == 2 && g >= 2) continue;
    #pragma unroll
    for (int xt = 0; xt < 4; ++xt) {
      const int pxl = xt * 16 + m;
      const int px = xb + pxl;
      float sx = (px + 0.5f) * 0.125f - 0.5f;
      float xq = floorf(sx);
      float fx = sx - xq;
      int x0c = max((int)xq, 0), x1c = min((int)xq + 1, 31);
      u16 r4[4];
      #pragma unroll
      for (int i = 0; i < 4; ++i) {
        int oc = 16 * t + 4 * g + i;
        float wgt = 1.f / (1.f + expf(-(acc[xt][t][i] + ((const float*)&bv[t])[i])));
        float bil = (1.f - fx) * s_yw[oc * 33 + x0c] + fx * s_yw[oc * 33 + x1c];
        r4[i] = f2b(wgt * bil);
      }
      uint2 pk;
      pk.x = (u32)r4[0] | ((u32)r4[1] << 16);
      pk.y = (u32)r4[2] | ((u32)r4[3] << 16);
      int byt = pxl * 80 + (16 * t + 4 * g) * 2;
      byt ^= ((pxl >> 3) & 7) << 4;
      *(uint2*)((char*)so + byt) = pk;
    }
  }
  const size_t rowu = (size_t)n * IMG_CL + ((size_t)(y + 1) * IW + (xb + 1)) * CH;
  #pragma unroll
  for (int q = 0; q < 5; ++q) {
    int byt = l * 80 + q * 16;
    byt ^= ((l >> 3) & 7) << 4;
    uint4 d = *(const uint4*)((const char*)so + byt);
    *(uint4*)(outcl + rowu + (size_t)l * 40 + q * 8) = d;
  }
}

extern "C" void kernel_launch(void* const* d_in, const int* in_sizes, int n_in,
                              void* d_out, int out_size, void* d_ws, size_t ws_size,
                              hipStream_t stream)
{
  const float* x       = (const float*)d_in[0];
  const float* conv_w  = (const float*)d_in[1];
  const float* conv_b  = (const float*)d_in[2];
  const float* ddct_w  = (const float*)d_in[3];
  const float* ddct_b  = (const float*)d_in[4];
  const float* dctc_w  = (const float*)d_in[5];
  const float* dctc_b  = (const float*)d_in[6];
  const float* w1_w    = (const float*)d_in[7];
  const float* w1_b    = (const float*)d_in[8];
  const float* w3_w    = (const float*)d_in[9];
  const float* w3_b    = (const float*)d_in[10];
  const float* after_w = (const float*)d_in[11];
  const float* after_b = (const float*)d_in[12];

  char* ws = (char*)d_ws;
  const size_t CLB = (size_t)8 * IMG_CL * 2;          // 42,600,960 B
  u16*   xcl    = (u16*)ws;
  u16*   cl_a   = (u16*)(ws + CLB);
  u16*   cl_b   = (u16*)(ws + 2 * CLB);
  float* small0 = (float*)(ws + 3 * CLB);             // 1,310,720 B
  float* small1 = (float*)(ws + 3 * CLB + 1310720);   // 1,310,720 B
  u16*   wt     = (u16*)(ws + 3 * CLB + 2621440);     // 184,320 B (5 sets)

  // 0. weight transform (5 sets) + input cl conversion + ring zeroing
  prep_w_k<<<360, 256, 0, stream>>>(conv_w, ddct_w, w1_w, after_w, w3_w, wt);
  prep_x_k<<<8 * IW, 256, 0, stream>>>(x, xcl, cl_a, cl_b);
  // 1. dct_feat = gelu(conv(x))                    -> cl_a
  convm_k<1, false, false><<<2048, 256, 0, stream>>>(xcl, wt, conv_b, nullptr, cl_a);
  // 2. dd = gelu(conv(dct_feat)) + dct_feat        -> cl_b
  convm_k<1, true, false><<<2048, 256, 0, stream>>>(cl_a, wt + WT_SET, ddct_b, cl_a, cl_b);
  // 3. depthwise strided conv                      -> small0
  dwconv_k<<<1280, 256, 0, stream>>>(cl_b, dctc_w, dctc_b, small0);
  // 4. per-block 8x8 iDCT                          -> small1
  idct8_k<<<1280, 256, 0, stream>>>(small0, small1);
  // 5. t1 = relu(conv(x, w1))                      -> cl_b (dd dead)
  convm_k<2, false, false><<<2048, 256, 0, stream>>>(xcl, wt + 2 * WT_SET, w1_b, nullptr, cl_b);
  // 6. prod = sigmoid(1x1(t1)) * bilinear(idct)    -> cl_a (dct_feat dead)
  wgtmul_k<<<2048, 256, 0, stream>>>(cl_b, wt + 4 * WT_SET, w3_b, small1, cl_a);
  // 7. out = conv(prod, after)                     -> d_out fp32 planar
  convm_k<0, false, true><<<2048, 256, 0, stream>>>(cl_a, wt + 3 * WT_SET, after_b, nullptr, (void*)d_out);
}

// Round 7
// 310.089 us; speedup vs baseline: 3.8458x; 1.0653x over previous
//
#include <hip/hip_runtime.h>

typedef unsigned short u16;
typedef unsigned int u32;
typedef __attribute__((ext_vector_type(8))) short bf16x8;
typedef __attribute__((ext_vector_type(4))) float f32x4;

#define CH 40
#define IW 258                   // ring-padded width (256 + 2)
#define IWCH (IW * CH)           // 10320
#define IMG_CL (IW * IW * CH)    // u16 elements per image, channel-last padded
#define WT_SET (48 * 384)        // u16 per weight set

#define GLDS16(g, l) __builtin_amdgcn_global_load_lds( \
    (const __attribute__((address_space(1))) void*)(g), \
    (__attribute__((address_space(3))) void*)(l), 16, 0, 0)

__device__ __forceinline__ float b2f(u16 u) {
  union { u32 i; float f; } v; v.i = ((u32)u) << 16; return v.f;
}
__device__ __forceinline__ u16 f2b(float f) {
  union { float f; u32 i; } v; v.f = f;
  u32 r = v.i + 0x7fffu + ((v.i >> 16) & 1u);
  return (u16)(r >> 16);
}
__device__ __forceinline__ u32 addbf2(u32 a, u32 b) {
  union { u32 i; float f; } lo_a, lo_b, hi_a, hi_b;
  lo_a.i = a << 16; lo_b.i = b << 16;
  hi_a.i = a & 0xffff0000u; hi_b.i = b & 0xffff0000u;
  float lo = lo_a.f + lo_b.f, hi = hi_a.f + hi_b.f;
  return (u32)f2b(lo) | ((u32)f2b(hi) << 16);
}
__device__ __forceinline__ float actf(float t, int ACT) {
  if (ACT == 1) return 0.5f * t * (1.f + erff(t * 0.70710678118654752f));
  if (ACT == 2) return fmaxf(t, 0.f);
  return t;
}

// ---- weights -> Wt bf16 [48][384] per set --------------------------------
// sets 0..3: 3x3 convs, k = dy*128 + dx*40 + ic ; set 4: w3 1x1, k = ic (pad)
__global__ __launch_bounds__(256)
void prep_w_k(const float* __restrict__ w0, const float* __restrict__ w1,
              const float* __restrict__ w2, const float* __restrict__ w3,
              const float* __restrict__ w4, u16* __restrict__ wt)
{
  int i = blockIdx.x * 256 + threadIdx.x;      // 5*48*384 = 92160
  if (i >= 5 * WT_SET) return;
  int k = i % 384;
  int oc = (i / 384) % 48;
  int set = i / WT_SET;
  u16 v = 0;
  if (set == 4) {
    if (oc < 40 && k < 40) v = f2b(w4[oc * 40 + k]);
  } else {
    int dy = k >> 7;
    int r = k & 127;
    if (oc < 40 && r < 120) {
      int dx = r / 40;
      int ic = r - dx * 40;
      const float* w = (set == 0) ? w0 : (set == 1) ? w1 : (set == 2) ? w2 : w3;
      v = f2b(w[((oc * 40 + ic) * 3 + dy) * 3 + dx]);
    }
  }
  wt[i] = v;
}

// ---- x fp32 planar -> xcl bf16 channel-last + zero rings of xcl, cla -----
__global__ __launch_bounds__(256)
void prep_x_k(const float* __restrict__ x, u16* __restrict__ xcl,
              u16* __restrict__ cla)
{
  const int n = blockIdx.x / IW;
  const int yr = blockIdx.x % IW;          // padded row 0..257
  const int t = threadIdx.x;
  const size_t base = (size_t)n * IMG_CL + (size_t)yr * IWCH;
  const uint4 z = {0u, 0u, 0u, 0u};

  if (yr == 0 || yr == IW - 1) {           // full ring row
    for (int i = t; i < IWCH / 8; i += 256) {
      ((uint4*)(xcl + base))[i] = z;
      ((uint4*)(cla + base))[i] = z;
    }
    return;
  }
  if (t < 5) {                             // left ring col (40 u16 = 5 x 16B)
    ((uint4*)(xcl + base))[t] = z;
    ((uint4*)(cla + base))[t] = z;
  } else if (t < 10) {                     // right ring col
    size_t b2 = base + (size_t)(IW - 1) * CH;
    ((uint4*)(xcl + b2))[t - 5] = z;
    ((uint4*)(cla + b2))[t - 5] = z;
  }
  const int y = yr - 1;
  const float* xp = x + (size_t)n * CH * 65536 + (size_t)y * 256 + t;
  __attribute__((aligned(16))) u16 buf[40];
  #pragma unroll
  for (int ic = 0; ic < 40; ++ic) buf[ic] = f2b(xp[(size_t)ic * 65536]);
  u16* dst = xcl + base + (size_t)(t + 1) * CH;
  #pragma unroll
  for (int q = 0; q < 5; ++q) ((uint4*)dst)[q] = ((const uint4*)buf)[q];
}

// ---- fused conv1 + conv5: one staging of x, two weight sets --------------
// out A = gelu(conv(x,wA)) -> cl ; out B = relu(conv(x,wB)) -> cl
__global__ __launch_bounds__(256, 3)
void fconv15_k(const u16* __restrict__ incl, const u16* __restrict__ wtA,
               const u16* __restrict__ wtB, const float* __restrict__ biasA,
               const float* __restrict__ biasB, u16* __restrict__ outA,
               u16* __restrict__ outB)
{
  __shared__ u16 s_in[6 * 66 * CH];        // 31680 B; reused as out-stage

  const int tid = threadIdx.x;
  const int q8 = (int)gridDim.x >> 3;
  const int bid = ((int)blockIdx.x & 7) * q8 + ((int)blockIdx.x >> 3);
  const int n = bid >> 8;
  const int tb = bid & 255;
  const int y0 = (tb >> 2) << 2;
  const int x0 = (tb & 3) << 6;

  const u16* src = incl + (size_t)n * IMG_CL + ((size_t)y0 * IW + x0) * CH;
  for (int k = 0; k < 8; ++k) {            // 1980 16B chunks, lane-linear LDS
    int i = tid + (k << 8);
    if (i < 1980) {
      int r = i / 330, o = i - r * 330;
      GLDS16(src + (size_t)r * IWCH + o * 8, s_in + i * 8);
    }
  }
  __syncthreads();

  const int w = tid >> 6;                  // wave -> output row y0+w
  const int l = tid & 63;
  const int g = l >> 4;
  const int m = l & 15;

  f32x4 accA[4][3], accB[4][3];
  #pragma unroll
  for (int xt = 0; xt < 4; ++xt)
    #pragma unroll
    for (int t = 0; t < 3; ++t) {
      accA[xt][t] = (f32x4){0.f, 0.f, 0.f, 0.f};
      accB[xt][t] = (f32x4){0.f, 0.f, 0.f, 0.f};
    }

  #pragma unroll
  for (int s = 0; s < 12; ++s) {
    const int dy = s >> 2;
    const int c = ((s & 3) << 2) + g;      // k-chunk id 0..15
    int dx, icb;
    if (c >= 15)      { dx = 0; icb = 0; }
    else if (c >= 10) { dx = 2; icb = (c - 10) * 8; }
    else if (c >= 5)  { dx = 1; icb = (c - 5) * 8; }
    else              { dx = 0; icb = c * 8; }
    const int abase = (w + dy) * (66 * CH) + (m + dx) * CH + icb;
    bf16x8 a0 = *(const bf16x8*)(s_in + abase);
    bf16x8 a1 = *(const bf16x8*)(s_in + abase + 16 * CH);
    bf16x8 a2 = *(const bf16x8*)(s_in + abase + 32 * CH);
    bf16x8 a3 = *(const bf16x8*)(s_in + abase + 48 * CH);
    const int wb = s * 32 + g * 8;
    #pragma unroll
    for (int t = 0; t < 3; ++t) {
      bf16x8 bA = *(const bf16x8*)(wtA + (m + 16 * t) * 384 + wb);
      bf16x8 bB = *(const bf16x8*)(wtB + (m + 16 * t) * 384 + wb);
      accA[0][t] = __builtin_amdgcn_mfma_f32_16x16x32_bf16(bA, a0, accA[0][t], 0, 0, 0);
      accA[1][t] = __builtin_amdgcn_mfma_f32_16x16x32_bf16(bA, a1, accA[1][t], 0, 0, 0);
      accA[2][t] = __builtin_amdgcn_mfma_f32_16x16x32_bf16(bA, a2, accA[2][t], 0, 0, 0);
      accA[3][t] = __builtin_amdgcn_mfma_f32_16x16x32_bf16(bA, a3, accA[3][t], 0, 0, 0);
      accB[0][t] = __builtin_amdgcn_mfma_f32_16x16x32_bf16(bB, a0, accB[0][t], 0, 0, 0);
      accB[1][t] = __builtin_amdgcn_mfma_f32_16x16x32_bf16(bB, a1, accB[1][t], 0, 0, 0);
      accB[2][t] = __builtin_amdgcn_mfma_f32_16x16x32_bf16(bB, a2, accB[2][t], 0, 0, 0);
      accB[3][t] = __builtin_amdgcn_mfma_f32_16x16x32_bf16(bB, a3, accB[3][t], 0, 0, 0);
    }
  }

  const int y = y0 + w;
  const size_t rowu = (size_t)n * IMG_CL + ((size_t)(y + 1) * IW + (x0 + 1)) * CH;
  __syncthreads();                         // all K-loop s_in reads done

  // FIX (round 6 bug): reuse ONE per-wave 6144 B region for both outputs.
  // Regions are wave-private (4 x 6144 B = 24576 B <= 31680 B); within-wave
  // write->read->write ordering is enforced by the compiler's lgkmcnt.
  u16* so = s_in + w * 3072;               // u16 offset -> w*6144 bytes
  #pragma unroll
  for (int which = 0; which < 2; ++which) {
    const float* bias = which ? biasB : biasA;
    const int ACT = which ? 2 : 1;
    f32x4 (*acc)[3] = which ? accB : accA;
    float4 bv[3];
    bv[0] = *(const float4*)(bias + 4 * g);
    bv[1] = *(const float4*)(bias + 16 + 4 * g);
    bv[2] = (g < 2) ? *(const float4*)(bias + 32 + 4 * g)
                    : make_float4(0.f, 0.f, 0.f, 0.f);
    #pragma unroll
    for (int t = 0; t < 3; ++t) {
      if (t == 2 && g >= 2) continue;
      #pragma unroll
      for (int xt = 0; xt < 4; ++xt) {
        const int pxl = xt * 16 + m;
        float v[4];
        #pragma unroll
        for (int i = 0; i < 4; ++i)
          v[i] = actf(acc[xt][t][i] + ((const float*)&bv[t])[i], ACT);
        uint2 pk;
        pk.x = (u32)f2b(v[0]) | ((u32)f2b(v[1]) << 16);
        pk.y = (u32)f2b(v[2]) | ((u32)f2b(v[3]) << 16);
        int byt = pxl * 80 + (16 * t + 4 * g) * 2;
        byt ^= ((pxl >> 3) & 7) << 4;
        *(uint2*)((char*)so + byt) = pk;
      }
    }
    u16* dst = which ? outB : outA;
    #pragma unroll
    for (int q = 0; q < 5; ++q) {
      int byt = l * 80 + q * 16;
      byt ^= ((l >> 3) & 7) << 4;
      uint4 d = *(const uint4*)((const char*)so + byt);
      *(uint4*)(dst + rowu + (size_t)l * 40 + q * 8) = d;
    }
  }
}

// ---- MFMA implicit-GEMM conv 3x3 pad 1, 8 rows x 64 px, 8 waves ----------
template<int ACT, bool RES, bool PLANAR_OUT>
__global__ __launch_bounds__(512, 4)
void convm_k(const u16* __restrict__ incl, const u16* __restrict__ wt,
             const float* __restrict__ bias, const u16* __restrict__ rescl,
             void* __restrict__ outp)
{
  __shared__ u16 s_in[10 * 66 * CH];       // 52800 B; head reused as out-stage

  const int tid = threadIdx.x;
  const int q8 = (int)gridDim.x >> 3;
  const int bid = ((int)blockIdx.x & 7) * q8 + ((int)blockIdx.x >> 3);
  const int n = bid >> 7;
  const int tb = bid & 127;
  const int y0 = (tb >> 2) << 3;           // 32 y-tiles of 8 rows
  const int x0 = (tb & 3) << 6;

  const u16* src = incl + (size_t)n * IMG_CL + ((size_t)y0 * IW + x0) * CH;
  for (int k = 0; k < 7; ++k) {            // 3300 16B chunks, lane-linear LDS
    int i = tid + (k << 9);
    if (i < 3300) {
      int r = i / 330, o = i - r * 330;
      GLDS16(src + (size_t)r * IWCH + o * 8, s_in + i * 8);
    }
  }
  __syncthreads();

  const int w = tid >> 6;                  // wave -> output row y0+w (0..7)
  const int l = tid & 63;
  const int g = l >> 4;
  const int m = l & 15;

  f32x4 acc[4][3];
  #pragma unroll
  for (int xt = 0; xt < 4; ++xt)
    #pragma unroll
    for (int t = 0; t < 3; ++t) acc[xt][t] = (f32x4){0.f, 0.f, 0.f, 0.f};

  bf16x8 aC[4], bC[3], aN[4], bN[3];
  auto lf = [&](int s, bf16x8* A, bf16x8* B) {
    const int dy = s >> 2;
    const int c = ((s & 3) << 2) + g;
    int dx, icb;
    if (c >= 15)      { dx = 0; icb = 0; }
    else if (c >= 10) { dx = 2; icb = (c - 10) * 8; }
    else if (c >= 5)  { dx = 1; icb = (c - 5) * 8; }
    else              { dx = 0; icb = c * 8; }
    const int abase = (w + dy) * (66 * CH) + (m + dx) * CH + icb;
    A[0] = *(const bf16x8*)(s_in + abase);
    A[1] = *(const bf16x8*)(s_in + abase + 16 * CH);
    A[2] = *(const bf16x8*)(s_in + abase + 32 * CH);
    A[3] = *(const bf16x8*)(s_in + abase + 48 * CH);
    const int wb = s * 32 + g * 8;
    B[0] = *(const bf16x8*)(wt + m * 384 + wb);
    B[1] = *(const bf16x8*)(wt + (m + 16) * 384 + wb);
    B[2] = *(const bf16x8*)(wt + (m + 32) * 384 + wb);
  };

  lf(0, aC, bC);
  #pragma unroll
  for (int s = 0; s < 12; ++s) {
    if (s < 11) lf(s + 1, aN, bN);
    #pragma unroll
    for (int t = 0; t < 3; ++t)
      #pragma unroll
      for (int xt = 0; xt < 4; ++xt)
        acc[xt][t] = PLANAR_OUT
          ? __builtin_amdgcn_mfma_f32_16x16x32_bf16(aC[xt], bC[t], acc[xt][t], 0, 0, 0)
          : __builtin_amdgcn_mfma_f32_16x16x32_bf16(bC[t], aC[xt], acc[xt][t], 0, 0, 0);
    if (s < 11) {
      #pragma unroll
      for (int q = 0; q < 4; ++q) aC[q] = aN[q];
      #pragma unroll
      for (int q = 0; q < 3; ++q) bC[q] = bN[q];
    }
  }

  const int y = y0 + w;

  if (PLANAR_OUT) {
    const float bv0 = bias[m];
    const float bv1 = bias[m + 16];
    const float bv2 = (m < 8) ? bias[m + 32] : 0.f;
    #pragma unroll
    for (int t = 0; t < 3; ++t) {
      const int oc = m + 16 * t;
      if (t == 2 && m >= 8) continue;
      const float bv = (t == 0) ? bv0 : (t == 1) ? bv1 : bv2;
      #pragma unroll
      for (int xt = 0; xt < 4; ++xt) {
        const int xb = x0 + xt * 16 + 4 * g;
        float v[4];
        #pragma unroll
        for (int i = 0; i < 4; ++i) v[i] = actf(acc[xt][t][i] + bv, ACT);
        *(float4*)((float*)outp + (((size_t)(n * CH + oc)) << 16) + ((size_t)y << 8) + xb)
            = make_float4(v[0], v[1], v[2], v[3]);
      }
    }
  } else {
    __syncthreads();
    u16* s_out = s_in + w * 3072;          // per-wave 6144 B (8 x 6144 <= 52800)
    float4 bv[3];
    bv[0] = *(const float4*)(bias + 4 * g);
    bv[1] = *(const float4*)(bias + 16 + 4 * g);
    bv[2] = (g < 2) ? *(const float4*)(bias + 32 + 4 * g)
                    : make_float4(0.f, 0.f, 0.f, 0.f);
    #pragma unroll
    for (int t = 0; t < 3; ++t) {
      if (t == 2 && g >= 2) continue;
      #pragma unroll
      for (int xt = 0; xt < 4; ++xt) {
        const int pxl = xt * 16 + m;
        float v[4];
        #pragma unroll
        for (int i = 0; i < 4; ++i)
          v[i] = actf(acc[xt][t][i] + ((const float*)&bv[t])[i], ACT);
        uint2 pk;
        pk.x = (u32)f2b(v[0]) | ((u32)f2b(v[1]) << 16);
        pk.y = (u32)f2b(v[2]) | ((u32)f2b(v[3]) << 16);
        int byt = pxl * 80 + (16 * t + 4 * g) * 2;
        byt ^= ((pxl >> 3) & 7) << 4;
        *(uint2*)((char*)s_out + byt) = pk;
      }
    }
    const size_t rowu = (size_t)n * IMG_CL + ((size_t)(y + 1) * IW + (x0 + 1)) * CH;
    #pragma unroll
    for (int q = 0; q < 5; ++q) {
      int byt = l * 80 + q * 16;
      byt ^= ((l >> 3) & 7) << 4;
      uint4 d = *(const uint4*)((const char*)s_out + byt);
      if (RES) {
        uint4 rv = *(const uint4*)(rescl + rowu + (size_t)l * 40 + q * 8);
        d.x = addbf2(d.x, rv.x); d.y = addbf2(d.y, rv.y);
        d.z = addbf2(d.z, rv.z); d.w = addbf2(d.w, rv.w);
      }
      *(uint4*)((u16*)outp + rowu + (size_t)l * 40 + q * 8) = d;
    }
  }
}

// ---- depthwise conv k3 s8 p2 d2 on cl bf16 -> planar f32 (8,40,32,32) ----
__global__ __launch_bounds__(256)
void dwconv_k(const u16* __restrict__ incl, const float* __restrict__ w,
              const float* __restrict__ b, float* __restrict__ out)
{
  int idx = blockIdx.x * 256 + threadIdx.x;
  if (idx >= 8 * 32 * 32 * CH) return;
  int c = idx % CH;
  int p = idx / CH;
  int ox = p & 31;
  int oy = (p >> 5) & 31;
  int n = p >> 10;
  float acc = b[c];
  const u16* ip = incl + (size_t)n * IMG_CL;
  #pragma unroll
  for (int dy = 0; dy < 3; ++dy) {
    int y = oy * 8 - 2 + dy * 2;
    if ((unsigned)y >= 256u) continue;
    #pragma unroll
    for (int dx = 0; dx < 3; ++dx) {
      int x = ox * 8 - 2 + dx * 2;
      if ((unsigned)x >= 256u) continue;
      acc += w[c * 9 + dy * 3 + dx] * b2f(ip[((size_t)(y + 1) * IW + (x + 1)) * CH + c]);
    }
  }
  out[((size_t)(n * CH + c) << 10) + oy * 32 + ox] = acc;
}

// ---- per-8x8-block iDCT on planar f32 32x32 ------------------------------
__global__ __launch_bounds__(256)
void idct8_k(const float* __restrict__ in, float* __restrict__ out)
{
  __shared__ float ctab[8];
  if (threadIdx.x < 8) {
    const float c_[8] = {1.f, 0.70710678118654752f, 0.f, -0.70710678118654752f,
                         -1.f, -0.70710678118654752f, 0.f, 0.70710678118654752f};
    ctab[threadIdx.x] = c_[threadIdx.x];
  }
  __syncthreads();
  int idx = blockIdx.x * 256 + threadIdx.x;
  if (idx >= 8 * CH * 32 * 32) return;
  int ox = idx & 31, oy = (idx >> 5) & 31, bc = idx >> 10;
  int k = oy & 7, lq = ox & 7;
  const float* ip = in + bc * 1024 + (oy & ~7) * 32 + (ox & ~7);
  float acc = 0.f;
  #pragma unroll
  for (int mm = 0; mm < 8; ++mm) {
    float rk = ctab[(k * mm) & 7];
    float s = 0.f;
    #pragma unroll
    for (int nn = 0; nn < 8; ++nn)
      s += ctab[(lq * nn) & 7] * ip[mm * 32 + nn];
    acc += rk * s;
  }
  out[idx] = acc * 0.125f;
}

// ---- MFMA 1x1 conv + sigmoid + bilinear(32->256) multiply; cl bf16 -------
__global__ __launch_bounds__(256)
void wgtmul_k(const u16* __restrict__ t1cl, const u16* __restrict__ wt3,
              const float* __restrict__ b3, const float* __restrict__ dct,
              u16* __restrict__ outcl)
{
  __shared__ float s_yw[40 * 33];
  __shared__ u16 s_out[4 * 3072];

  const int q8 = (int)gridDim.x >> 3;
  const int bid = ((int)blockIdx.x & 7) * q8 + ((int)blockIdx.x >> 3);
  const int n = bid >> 8;
  const int y = bid & 255;
  const int tid = threadIdx.x;

  float sy = (y + 0.5f) * 0.125f - 0.5f;
  float yq = floorf(sy);
  float fy = sy - yq;
  int y0c = max((int)yq, 0), y1c = min((int)yq + 1, 31);

  for (int i = tid; i < 1280; i += 256) {
    int oc = i >> 5, c = i & 31;
    const float* sp = dct + ((size_t)(n * CH + oc) << 10);
    s_yw[oc * 33 + c] = (1.f - fy) * sp[y0c * 32 + c] + fy * sp[y1c * 32 + c];
  }
  __syncthreads();

  const int w = tid >> 6;
  const int l = tid & 63;
  const int g = l >> 4;
  const int m = l & 15;
  const int xb = w << 6;

  const u16* tp = t1cl + (size_t)n * IMG_CL + ((size_t)(y + 1) * IW + 1) * CH;

  f32x4 acc[4][3];
  #pragma unroll
  for (int xt = 0; xt < 4; ++xt)
    #pragma unroll
    for (int t = 0; t < 3; ++t) acc[xt][t] = (f32x4){0.f, 0.f, 0.f, 0.f};

  #pragma unroll
  for (int xt = 0; xt < 4; ++xt) {
    const u16* ap = tp + (size_t)(xb + xt * 16 + m) * CH;
    bf16x8 a0 = *(const bf16x8*)(ap + 8 * g);
    bf16x8 a1 = *(const bf16x8*)(ap + 32 + 8 * g);
    #pragma unroll
    for (int t = 0; t < 3; ++t) {
      bf16x8 b0 = *(const bf16x8*)(wt3 + (m + 16 * t) * 384 + 8 * g);
      bf16x8 b1 = *(const bf16x8*)(wt3 + (m + 16 * t) * 384 + 32 + 8 * g);
      acc[xt][t] = __builtin_amdgcn_mfma_f32_16x16x32_bf16(b0, a0, acc[xt][t], 0, 0, 0);
      acc[xt][t] = __builtin_amdgcn_mfma_f32_16x16x32_bf16(b1, a1, acc[xt][t], 0, 0, 0);
    }
  }

  u16* so = s_out + w * 3072;
  float4 bv[3];
  bv[0] = *(const float4*)(b3 + 4 * g);
  bv[1] = *(const float4*)(b3 + 16 + 4 * g);
  bv[2] = (g < 2) ? *(const float4*)(b3 + 32 + 4 * g) : make_float4(0.f, 0.f, 0.f, 0.f);
  #pragma unroll
  for (int t = 0; t < 3; ++t) {
    if (t == 2 && g >= 2) continue;
    #pragma unroll
    for (int xt = 0; xt < 4; ++xt) {
      const int pxl = xt * 16 + m;
      const int px = xb + pxl;
      float sx = (px + 0.5f) * 0.125f - 0.5f;
      float xq = floorf(sx);
      float fx = sx - xq;
      int x0c = max((int)xq, 0), x1c = min((int)xq + 1, 31);
      u16 r4[4];
      #pragma unroll
      for (int i = 0; i < 4; ++i) {
        int oc = 16 * t + 4 * g + i;
        float wgt = 1.f / (1.f + expf(-(acc[xt][t][i] + ((const float*)&bv[t])[i])));
        float bil = (1.f - fx) * s_yw[oc * 33 + x0c] + fx * s_yw[oc * 33 + x1c];
        r4[i] = f2b(wgt * bil);
      }
      uint2 pk;
      pk.x = (u32)r4[0] | ((u32)r4[1] << 16);
      pk.y = (u32)r4[2] | ((u32)r4[3] << 16);
      int byt = pxl * 80 + (16 * t + 4 * g) * 2;
      byt ^= ((pxl >> 3) & 7) << 4;
      *(uint2*)((char*)so + byt) = pk;
    }
  }
  const size_t rowu = (size_t)n * IMG_CL + ((size_t)(y + 1) * IW + (xb + 1)) * CH;
  #pragma unroll
  for (int q = 0; q < 5; ++q) {
    int byt = l * 80 + q * 16;
    byt ^= ((l >> 3) & 7) << 4;
    uint4 d = *(const uint4*)((const char*)so + byt);
    *(uint4*)(outcl + rowu + (size_t)l * 40 + q * 8) = d;
  }
}

extern "C" void kernel_launch(void* const* d_in, const int* in_sizes, int n_in,
                              void* d_out, int out_size, void* d_ws, size_t ws_size,
                              hipStream_t stream)
{
  const float* x       = (const float*)d_in[0];
  const float* conv_w  = (const float*)d_in[1];
  const float* conv_b  = (const float*)d_in[2];
  const float* ddct_w  = (const float*)d_in[3];
  const float* ddct_b  = (const float*)d_in[4];
  const float* dctc_w  = (const float*)d_in[5];
  const float* dctc_b  = (const float*)d_in[6];
  const float* w1_w    = (const float*)d_in[7];
  const float* w1_b    = (const float*)d_in[8];
  const float* w3_w    = (const float*)d_in[9];
  const float* w3_b    = (const float*)d_in[10];
  const float* after_w = (const float*)d_in[11];
  const float* after_b = (const float*)d_in[12];

  char* ws = (char*)d_ws;
  const size_t CLB = (size_t)8 * IMG_CL * 2;          // 42,600,960 B
  u16*   xcl    = (u16*)ws;                           // x, later dd
  u16*   cl_a   = (u16*)(ws + CLB);                   // dct_feat, later prod
  u16*   cl_c   = (u16*)(ws + 2 * CLB);               // t1
  float* small0 = (float*)(ws + 3 * CLB);             // 1,310,720 B
  float* small1 = (float*)(ws + 3 * CLB + 1310720);   // 1,310,720 B
  u16*   wt     = (u16*)(ws + 3 * CLB + 2621440);     // 184,320 B (5 sets)

  // 0. weight transform + input cl conversion + ring zeroing (xcl, cl_a)
  prep_w_k<<<360, 256, 0, stream>>>(conv_w, ddct_w, w1_w, after_w, w3_w, wt);
  prep_x_k<<<8 * IW, 256, 0, stream>>>(x, xcl, cl_a);
  // 1+5. dct_feat = gelu(conv(x)) -> cl_a ; t1 = relu(conv(x,w1)) -> cl_c
  fconv15_k<<<2048, 256, 0, stream>>>(xcl, wt, wt + 2 * WT_SET, conv_b, w1_b,
                                      cl_a, cl_c);
  // 2. dd = gelu(conv(dct_feat)) + dct_feat        -> xcl (x dead)
  convm_k<1, true, false><<<1024, 512, 0, stream>>>(cl_a, wt + WT_SET, ddct_b, cl_a, xcl);
  // 3. depthwise strided conv                      -> small0
  dwconv_k<<<1280, 256, 0, stream>>>(xcl, dctc_w, dctc_b, small0);
  // 4. per-block 8x8 iDCT                          -> small1
  idct8_k<<<1280, 256, 0, stream>>>(small0, small1);
  // 6. prod = sigmoid(1x1(t1)) * bilinear(idct)    -> cl_a (dct_feat dead)
  wgtmul_k<<<2048, 256, 0, stream>>>(cl_c, wt + 4 * WT_SET, w3_b, small1, cl_a);
  // 7. out = conv(prod, after)                     -> d_out fp32 planar
  convm_k<0, false, true><<<1024, 512, 0, stream>>>(cl_a, wt + 3 * WT_SET, after_b, nullptr, (void*)d_out);
}